// Round 2
// baseline (370.488 us; speedup 1.0000x reference)
//
#include <hip/hip_runtime.h>

// HybridAttention: out[b,s,h*64+d] = sum_k ( mask? (Q·K^T)*0.125 : -1e9 ) * V
// Q=x@wq^T, K=x@wk^T, V=x@wv^T ; B=4,S=2048,D=1024,H=16,dk=64 ; NO softmax.
//
// Pipeline: k_convert (fp32->bf16) -> k_flags (mask tile AND-reduce)
//           -> k_proj (3x bf16 MFMA GEMM; V written transposed [b,h,d,s])
//           -> k_attn (fused QK^T -> scale/mask -> PV, flash-style, no softmax)

using u16 = unsigned short;
typedef __attribute__((ext_vector_type(8))) short  short8;   // 8 bf16 (4 VGPRs)
typedef __attribute__((ext_vector_type(4))) float  f32x4;
typedef __attribute__((ext_vector_type(4))) unsigned short u16x4;
typedef __attribute__((ext_vector_type(4))) int    i32x4;

#define DEV static __device__ __forceinline__

DEV u16 f2b(float f) {  // fp32 -> bf16 RNE
  unsigned u = __float_as_uint(f);
  return (u16)((u + 0x7FFFu + ((u >> 16) & 1u)) >> 16);
}

template <typename T>
DEV void gload_lds16(const T* g, T* l) {  // 16B global -> LDS, dest = wave-uniform base + lane*16
  __builtin_amdgcn_global_load_lds((const __attribute__((address_space(1))) unsigned int*)g,
                                   (__attribute__((address_space(3))) unsigned int*)l, 16, 0, 0);
}

// ---------------- convert x, wq, wk, wv to bf16 ----------------
__global__ __launch_bounds__(256) void k_convert(const float* __restrict__ x,
                                                 const float* __restrict__ wq,
                                                 const float* __restrict__ wk,
                                                 const float* __restrict__ wv,
                                                 u16* __restrict__ xb, u16* __restrict__ wb) {
  const int NX4 = 2097152;  // 8388608/4
  const int NW4 = 262144;   // 1048576/4
  const int total = NX4 + 3 * NW4;
  for (int i = blockIdx.x * blockDim.x + threadIdx.x; i < total; i += gridDim.x * blockDim.x) {
    const float4* src; u16* dst; int j;
    if (i < NX4) { src = (const float4*)x; dst = xb; j = i; }
    else {
      int tw = i - NX4; int wsel = tw >> 18; j = tw & (NW4 - 1);
      src = (const float4*)(wsel == 0 ? wq : (wsel == 1 ? wk : wv));
      dst = wb + (size_t)wsel * 1048576;
    }
    float4 v = src[j];
    u16x4 o; o[0] = f2b(v.x); o[1] = f2b(v.y); o[2] = f2b(v.z); o[3] = f2b(v.w);
    *(u16x4*)(dst + (size_t)j * 4) = o;
  }
}

// ---------------- per-tile mask flags: 1 if any zero in (b, qtile128, ktile64) ----------------
__global__ __launch_bounds__(256) void k_flags(const int* __restrict__ mask, int* __restrict__ flags) {
  const int bx = blockIdx.x;                 // 4*16*32 = 2048 tiles
  const int b_ = bx >> 9, rem = bx & 511, qt = rem >> 5, kt = rem & 31;
  const int t = threadIdx.x;
  const size_t base = ((size_t)(b_ * 2048 + qt * 128)) * 2048 + kt * 64;
  int az = 0;
#pragma unroll
  for (int kk = 0; kk < 8; ++kk) {
    int i = t + kk * 256;
    int row = i >> 4, c4 = i & 15;
    i32x4 v = *(const i32x4*)(mask + base + (size_t)row * 2048 + c4 * 4);
    az |= (v.x == 0) | (v.y == 0) | (v.z == 0) | (v.w == 0);
  }
  __shared__ int red[4];
  unsigned long long bal = __ballot(az != 0);
  if ((t & 63) == 0) red[t >> 6] = (bal != 0ull);
  __syncthreads();
  if (t == 0) flags[bx] = red[0] | red[1] | red[2] | red[3];
}

// ---------------- projection GEMM: C[m,n] = sum_k X[m,k] * W[n,k] ----------------
// which=0 -> qb[b,h,s,d], which=1 -> kb[b,h,s,d], which=2 -> vtb[b,h,d,s] (transposed write)
__global__ __launch_bounds__(256, 2) void k_proj(const u16* __restrict__ xb, const u16* __restrict__ wb,
                                                 u16* __restrict__ qb, u16* __restrict__ kb,
                                                 u16* __restrict__ vtb) {
  __shared__ u16 lA[128 * 64];
  __shared__ u16 lB[128 * 64];
  const int t = threadIdx.x, wid = t >> 6, lid = t & 63, ln = lid & 15, hi = lid >> 4;
  const int mt = blockIdx.x >> 3, nt = blockIdx.x & 7, which = blockIdx.y;
  const u16* wsrc = wb + (size_t)which * (1024 * 1024);
  const int wm = wid >> 1, wn = wid & 1;

  f32x4 acc[4][4];
#pragma unroll
  for (int a = 0; a < 4; ++a)
#pragma unroll
    for (int b2 = 0; b2 < 4; ++b2) acc[a][b2] = (f32x4){0.f, 0.f, 0.f, 0.f};

  for (int kt = 0; kt < 16; ++kt) {
    __syncthreads();
#pragma unroll
    for (int i = 0; i < 4; ++i) {
      int e = (i * 256 + t) * 8, row = e >> 6, col = e & 63;
      gload_lds16(xb + (size_t)(mt * 128 + row) * 1024 + kt * 64 + col, &lA[i * 2048 + wid * 512]);
      gload_lds16(wsrc + (size_t)(nt * 128 + row) * 1024 + kt * 64 + col, &lB[i * 2048 + wid * 512]);
    }
    __syncthreads();
#pragma unroll
    for (int ks = 0; ks < 2; ++ks) {
      short8 af[4], bfr[4];
#pragma unroll
      for (int mi = 0; mi < 4; ++mi) af[mi] = *(const short8*)&lA[(wm * 64 + mi * 16 + ln) * 64 + ks * 32 + hi * 8];
#pragma unroll
      for (int ni = 0; ni < 4; ++ni) bfr[ni] = *(const short8*)&lB[(wn * 64 + ni * 16 + ln) * 64 + ks * 32 + hi * 8];
#pragma unroll
      for (int mi = 0; mi < 4; ++mi)
#pragma unroll
        for (int ni = 0; ni < 4; ++ni)
          acc[mi][ni] = __builtin_amdgcn_mfma_f32_16x16x32_bf16(af[mi], bfr[ni], acc[mi][ni], 0, 0, 0);
    }
  }

  const int m0 = mt * 128 + wm * 64, n0 = nt * 128 + wn * 64;
  if (which == 2) {
    // V transposed: vtb[((b*16+h)*64+d)*2048 + s] ; lane's 4 regs = 4 consecutive s -> 8B store
#pragma unroll
    for (int mi = 0; mi < 4; ++mi)
#pragma unroll
      for (int ni = 0; ni < 4; ++ni) {
        int mm = m0 + mi * 16 + hi * 4;
        int nn = n0 + ni * 16 + ln;
        int bb = mm >> 11, s0 = mm & 2047, hh = nn >> 6, dd = nn & 63;
        u16x4 pk;
#pragma unroll
        for (int r = 0; r < 4; ++r) pk[r] = f2b(acc[mi][ni][r]);
        *(u16x4*)(vtb + ((size_t)((bb * 16 + hh) * 64 + dd)) * 2048 + s0) = pk;
      }
  } else {
    u16* dst = (which == 1) ? kb : qb;
#pragma unroll
    for (int mi = 0; mi < 4; ++mi)
#pragma unroll
      for (int ni = 0; ni < 4; ++ni) {
        int nn = n0 + ni * 16 + ln;
        int hh = nn >> 6, dd = nn & 63;
#pragma unroll
        for (int r = 0; r < 4; ++r) {
          int m = m0 + mi * 16 + hi * 4 + r;
          int bb = m >> 11, ss = m & 2047;
          dst[((size_t)(bb * 16 + hh) * 2048 + ss) * 64 + dd] = f2b(acc[mi][ni][r]);
        }
      }
  }
}

// ---------------- fused attention (no softmax) ----------------
// grid: (qtile=16, bh=64). 4 waves, each owns 32 q-rows. BK=64 kv per iter.
__global__ __launch_bounds__(256, 2) void k_attn(const u16* __restrict__ qb, const u16* __restrict__ kb,
                                                 const u16* __restrict__ vtb, const int* __restrict__ mask,
                                                 const int* __restrict__ flags, float* __restrict__ out) {
  __shared__ u16 lQ[128 * 64];
  __shared__ u16 lK[64 * 64];
  __shared__ u16 lVt[64 * 64];
  __shared__ u16 lP[128 * 64];
  const int t = threadIdx.x, wid = t >> 6, lid = t & 63, ln = lid & 15, hi = lid >> 4;
  const int qt = blockIdx.x, bh = blockIdx.y, b_ = bh >> 4, h = bh & 15;
  const u16* Qg = qb + (size_t)bh * (2048 * 64);
  const u16* Kg = kb + (size_t)bh * (2048 * 64);
  const u16* Vg = vtb + (size_t)bh * (64 * 2048);
  const int* flagp = flags + (b_ * 16 + qt) * 32;
  const int* maskp = mask + (size_t)b_ * (2048 * 2048);

  // stage Q tile [128][64] once
#pragma unroll
  for (int i = 0; i < 4; ++i) {
    int e = (i * 256 + t) * 8, row = e >> 6, col = e & 63;
    gload_lds16(Qg + (size_t)(qt * 128 + row) * 64 + col, &lQ[i * 2048 + wid * 512]);
  }
  __syncthreads();
  short8 aq[2][2];
#pragma unroll
  for (int mi = 0; mi < 2; ++mi)
#pragma unroll
    for (int ks = 0; ks < 2; ++ks)
      aq[mi][ks] = *(const short8*)&lQ[(wid * 32 + mi * 16 + ln) * 64 + ks * 32 + hi * 8];

  f32x4 ao[2][4];
#pragma unroll
  for (int mi = 0; mi < 2; ++mi)
#pragma unroll
    for (int ni = 0; ni < 4; ++ni) ao[mi][ni] = (f32x4){0.f, 0.f, 0.f, 0.f};

  for (int kt = 0; kt < 32; ++kt) {
    __syncthreads();
#pragma unroll
    for (int i = 0; i < 2; ++i) {
      int e = (i * 256 + t) * 8, row = e >> 6, col = e & 63;
      gload_lds16(Kg + (size_t)(kt * 64 + row) * 64 + col, &lK[i * 2048 + wid * 512]);
      gload_lds16(Vg + (size_t)row * 2048 + kt * 64 + col, &lVt[i * 2048 + wid * 512]);
    }
    __syncthreads();

    // S = Q K^T  (per wave: 32 q-rows x 64 kv)
    f32x4 sa[2][4];
#pragma unroll
    for (int mi = 0; mi < 2; ++mi)
#pragma unroll
      for (int ni = 0; ni < 4; ++ni) sa[mi][ni] = (f32x4){0.f, 0.f, 0.f, 0.f};
#pragma unroll
    for (int ks = 0; ks < 2; ++ks) {
#pragma unroll
      for (int ni = 0; ni < 4; ++ni) {
        short8 bk = *(const short8*)&lK[(ni * 16 + ln) * 64 + ks * 32 + hi * 8];
        sa[0][ni] = __builtin_amdgcn_mfma_f32_16x16x32_bf16(aq[0][ks], bk, sa[0][ni], 0, 0, 0);
        sa[1][ni] = __builtin_amdgcn_mfma_f32_16x16x32_bf16(aq[1][ks], bk, sa[1][ni], 0, 0, 0);
      }
    }

    // scale + (rare) mask + convert to bf16 P in wave-private LDS region
    int flg = flagp[kt];
#pragma unroll
    for (int mi = 0; mi < 2; ++mi)
#pragma unroll
      for (int ni = 0; ni < 4; ++ni) {
        int qrow = wid * 32 + mi * 16 + hi * 4;
        int kcol = ni * 16 + ln;
#pragma unroll
        for (int r = 0; r < 4; ++r) {
          float p = sa[mi][ni][r] * 0.125f;
          if (flg) {
            int mv = maskp[(size_t)(qt * 128 + qrow + r) * 2048 + kt * 64 + kcol];
            if (mv == 0) p = -1e9f;
          }
          lP[(qrow + r) * 64 + kcol] = f2b(p);
        }
      }

    // O += P @ V   (V staged transposed: lVt[d][kv])
#pragma unroll
    for (int ks = 0; ks < 2; ++ks) {
      short8 ap0 = *(const short8*)&lP[(wid * 32 + ln) * 64 + ks * 32 + hi * 8];
      short8 ap1 = *(const short8*)&lP[(wid * 32 + 16 + ln) * 64 + ks * 32 + hi * 8];
#pragma unroll
      for (int ni = 0; ni < 4; ++ni) {
        short8 bv = *(const short8*)&lVt[(ni * 16 + ln) * 64 + ks * 32 + hi * 8];
        ao[0][ni] = __builtin_amdgcn_mfma_f32_16x16x32_bf16(ap0, bv, ao[0][ni], 0, 0, 0);
        ao[1][ni] = __builtin_amdgcn_mfma_f32_16x16x32_bf16(ap1, bv, ao[1][ni], 0, 0, 0);
      }
    }
  }

  float* op = out + ((size_t)b_ * 2048 + qt * 128) * 1024 + h * 64;
#pragma unroll
  for (int mi = 0; mi < 2; ++mi)
#pragma unroll
    for (int ni = 0; ni < 4; ++ni)
#pragma unroll
      for (int r = 0; r < 4; ++r)
        op[(size_t)(wid * 32 + mi * 16 + hi * 4 + r) * 1024 + ni * 16 + ln] = ao[mi][ni][r];
}

// ---------------- launch ----------------
extern "C" void kernel_launch(void* const* d_in, const int* in_sizes, int n_in,
                              void* d_out, int out_size, void* d_ws, size_t ws_size,
                              hipStream_t stream) {
  const float* x   = (const float*)d_in[0];
  const int*  mask = (const int*)d_in[1];
  const float* wq  = (const float*)d_in[2];
  const float* wk  = (const float*)d_in[3];
  const float* wv  = (const float*)d_in[4];
  float* out = (float*)d_out;

  char* ws = (char*)d_ws;
  const size_t XB_OFF = 0;                 // 16 MiB  x bf16
  const size_t WB_OFF = 16777216;          // 6 MiB   wq|wk|wv bf16
  const size_t QB_OFF = 23068672;          // 16 MiB  Q [b,h,s,d]
  const size_t KB_OFF = 39845888;          // 16 MiB  K [b,h,s,d]
  const size_t VT_OFF = 56623104;          // 16 MiB  V^T [b,h,d,s]
  const size_t FL_OFF = 73400320;          // 8 KiB   tile flags
  if (ws_size < FL_OFF + 8192) return;     // insufficient workspace (unexpected)

  u16* xb  = (u16*)(ws + XB_OFF);
  u16* wb  = (u16*)(ws + WB_OFF);
  u16* qb  = (u16*)(ws + QB_OFF);
  u16* kb  = (u16*)(ws + KB_OFF);
  u16* vtb = (u16*)(ws + VT_OFF);
  int* flags = (int*)(ws + FL_OFF);

  k_convert<<<2048, 256, 0, stream>>>(x, wq, wk, wv, xb, wb);
  k_flags<<<2048, 256, 0, stream>>>(mask, flags);
  k_proj<<<dim3(512, 3), 256, 0, stream>>>(xb, wb, qb, kb, vtb);
  k_attn<<<dim3(16, 64), 256, 0, stream>>>(qb, kb, vtb, mask, flags, out);
}

// Round 4
// 326.900 us; speedup vs baseline: 1.1333x; 1.1333x over previous
//
#include <hip/hip_runtime.h>

// HybridAttention: out[b,s,h*64+d] = sum_k ( mask? (Q·K^T)*0.125 : -1e9 ) * V
// Q=x@wq^T, K=x@wk^T, V=x@wv^T ; B=4,S=2048,D=1024,H=16,dk=64 ; NO softmax.
//
// R2 change: XOR-swizzle (T2, byte^((row&7)<<4)) on ALL row-major [R][64]-u16
// LDS tiles (lA,lB,lQ,lK,lVt,lP). Staging keeps LDS dest linear and
// pre-swizzles the GLOBAL source column (m173 pattern, rule #21).

using u16 = unsigned short;
typedef __attribute__((ext_vector_type(8))) short  short8;   // 8 bf16 (4 VGPRs)
typedef __attribute__((ext_vector_type(4))) float  f32x4;
typedef __attribute__((ext_vector_type(4))) unsigned short u16x4;
typedef __attribute__((ext_vector_type(4))) int    i32x4;

#define DEV static __device__ __forceinline__

DEV u16 f2b(float f) {  // fp32 -> bf16 RNE
  unsigned u = __float_as_uint(f);
  return (u16)((u + 0x7FFFu + ((u >> 16) & 1u)) >> 16);
}

// swizzled u16 index into a [rows][64] u16 LDS tile (row stride 128B)
DEV int swz(int row, int col) { return (row << 6) + (col ^ ((row & 7) << 3)); }

template <typename T>
DEV void gload_lds16(const T* g, T* l) {  // 16B global -> LDS, dest = wave-uniform base + lane*16
  __builtin_amdgcn_global_load_lds((const __attribute__((address_space(1))) unsigned int*)g,
                                   (__attribute__((address_space(3))) unsigned int*)l, 16, 0, 0);
}

// ---------------- convert x, wq, wk, wv to bf16 ----------------
__global__ __launch_bounds__(256) void k_convert(const float* __restrict__ x,
                                                 const float* __restrict__ wq,
                                                 const float* __restrict__ wk,
                                                 const float* __restrict__ wv,
                                                 u16* __restrict__ xb, u16* __restrict__ wb) {
  const int NX4 = 2097152;  // 8388608/4
  const int NW4 = 262144;   // 1048576/4
  const int total = NX4 + 3 * NW4;
  for (int i = blockIdx.x * blockDim.x + threadIdx.x; i < total; i += gridDim.x * blockDim.x) {
    const float4* src; u16* dst; int j;
    if (i < NX4) { src = (const float4*)x; dst = xb; j = i; }
    else {
      int tw = i - NX4; int wsel = tw >> 18; j = tw & (NW4 - 1);
      src = (const float4*)(wsel == 0 ? wq : (wsel == 1 ? wk : wv));
      dst = wb + (size_t)wsel * 1048576;
    }
    float4 v = src[j];
    u16x4 o; o[0] = f2b(v.x); o[1] = f2b(v.y); o[2] = f2b(v.z); o[3] = f2b(v.w);
    *(u16x4*)(dst + (size_t)j * 4) = o;
  }
}

// ---------------- per-tile mask flags: 1 if any zero in (b, qtile128, ktile64) ----------------
__global__ __launch_bounds__(256) void k_flags(const int* __restrict__ mask, int* __restrict__ flags) {
  const int bx = blockIdx.x;                 // 4*16*32 = 2048 tiles
  const int b_ = bx >> 9, rem = bx & 511, qt = rem >> 5, kt = rem & 31;
  const int t = threadIdx.x;
  const size_t base = ((size_t)(b_ * 2048 + qt * 128)) * 2048 + kt * 64;
  int az = 0;
#pragma unroll
  for (int kk = 0; kk < 8; ++kk) {
    int i = t + kk * 256;
    int row = i >> 4, c4 = i & 15;
    i32x4 v = *(const i32x4*)(mask + base + (size_t)row * 2048 + c4 * 4);
    az |= (v.x == 0) | (v.y == 0) | (v.z == 0) | (v.w == 0);
  }
  __shared__ int red[4];
  unsigned long long bal = __ballot(az != 0);
  if ((t & 63) == 0) red[t >> 6] = (bal != 0ull);
  __syncthreads();
  if (t == 0) flags[bx] = red[0] | red[1] | red[2] | red[3];
}

// ---------------- projection GEMM: C[m,n] = sum_k X[m,k] * W[n,k] ----------------
// which=0 -> qb[b,h,s,d], which=1 -> kb[b,h,s,d], which=2 -> vtb[b,h,d,s] (transposed write)
__global__ __launch_bounds__(256, 2) void k_proj(const u16* __restrict__ xb, const u16* __restrict__ wb,
                                                 u16* __restrict__ qb, u16* __restrict__ kb,
                                                 u16* __restrict__ vtb) {
  __shared__ u16 lA[128 * 64];
  __shared__ u16 lB[128 * 64];
  const int t = threadIdx.x, wid = t >> 6, lid = t & 63, ln = lid & 15, hi = lid >> 4;
  const int mt = blockIdx.x >> 3, nt = blockIdx.x & 7, which = blockIdx.y;
  const u16* wsrc = wb + (size_t)which * (1024 * 1024);
  const int wm = wid >> 1, wn = wid & 1;

  f32x4 acc[4][4];
#pragma unroll
  for (int a = 0; a < 4; ++a)
#pragma unroll
    for (int b2 = 0; b2 < 4; ++b2) acc[a][b2] = (f32x4){0.f, 0.f, 0.f, 0.f};

  for (int kt = 0; kt < 16; ++kt) {
    __syncthreads();
#pragma unroll
    for (int i = 0; i < 4; ++i) {
      int e = (i * 256 + t) * 8, row = e >> 6;
      int c = (e & 63) ^ ((row & 7) << 3);  // pre-swizzled global source column
      gload_lds16(xb + (size_t)(mt * 128 + row) * 1024 + kt * 64 + c, &lA[i * 2048 + wid * 512]);
      gload_lds16(wsrc + (size_t)(nt * 128 + row) * 1024 + kt * 64 + c, &lB[i * 2048 + wid * 512]);
    }
    __syncthreads();
#pragma unroll
    for (int ks = 0; ks < 2; ++ks) {
      short8 af[4], bfr[4];
#pragma unroll
      for (int mi = 0; mi < 4; ++mi) af[mi] = *(const short8*)&lA[swz(wm * 64 + mi * 16 + ln, ks * 32 + hi * 8)];
#pragma unroll
      for (int ni = 0; ni < 4; ++ni) bfr[ni] = *(const short8*)&lB[swz(wn * 64 + ni * 16 + ln, ks * 32 + hi * 8)];
#pragma unroll
      for (int mi = 0; mi < 4; ++mi)
#pragma unroll
        for (int ni = 0; ni < 4; ++ni)
          acc[mi][ni] = __builtin_amdgcn_mfma_f32_16x16x32_bf16(af[mi], bfr[ni], acc[mi][ni], 0, 0, 0);
    }
  }

  const int m0 = mt * 128 + wm * 64, n0 = nt * 128 + wn * 64;
  if (which == 2) {
    // V transposed: vtb[((b*16+h)*64+d)*2048 + s] ; lane's 4 regs = 4 consecutive s -> 8B store
#pragma unroll
    for (int mi = 0; mi < 4; ++mi)
#pragma unroll
      for (int ni = 0; ni < 4; ++ni) {
        int mm = m0 + mi * 16 + hi * 4;
        int nn = n0 + ni * 16 + ln;
        int bb = mm >> 11, s0 = mm & 2047, hh = nn >> 6, dd = nn & 63;
        u16x4 pk;
#pragma unroll
        for (int r = 0; r < 4; ++r) pk[r] = f2b(acc[mi][ni][r]);
        *(u16x4*)(vtb + ((size_t)((bb * 16 + hh) * 64 + dd)) * 2048 + s0) = pk;
      }
  } else {
    u16* dst = (which == 1) ? kb : qb;
#pragma unroll
    for (int mi = 0; mi < 4; ++mi)
#pragma unroll
      for (int ni = 0; ni < 4; ++ni) {
        int nn = n0 + ni * 16 + ln;
        int hh = nn >> 6, dd = nn & 63;
#pragma unroll
        for (int r = 0; r < 4; ++r) {
          int m = m0 + mi * 16 + hi * 4 + r;
          int bb = m >> 11, ss = m & 2047;
          dst[((size_t)(bb * 16 + hh) * 2048 + ss) * 64 + dd] = f2b(acc[mi][ni][r]);
        }
      }
  }
}

// ---------------- fused attention (no softmax) ----------------
// grid: (qtile=16, bh=64). 4 waves, each owns 32 q-rows. BK=64 kv per iter.
__global__ __launch_bounds__(256, 2) void k_attn(const u16* __restrict__ qb, const u16* __restrict__ kb,
                                                 const u16* __restrict__ vtb, const int* __restrict__ mask,
                                                 const int* __restrict__ flags, float* __restrict__ out) {
  __shared__ u16 lQ[128 * 64];
  __shared__ u16 lK[64 * 64];
  __shared__ u16 lVt[64 * 64];
  __shared__ u16 lP[128 * 64];
  const int t = threadIdx.x, wid = t >> 6, lid = t & 63, ln = lid & 15, hi = lid >> 4;
  const int qt = blockIdx.x, bh = blockIdx.y, b_ = bh >> 4, h = bh & 15;
  const u16* Qg = qb + (size_t)bh * (2048 * 64);
  const u16* Kg = kb + (size_t)bh * (2048 * 64);
  const u16* Vg = vtb + (size_t)bh * (64 * 2048);
  const int* flagp = flags + (b_ * 16 + qt) * 32;
  const int* maskp = mask + (size_t)b_ * (2048 * 2048);

  // stage Q tile [128][64] once (swizzled)
#pragma unroll
  for (int i = 0; i < 4; ++i) {
    int e = (i * 256 + t) * 8, row = e >> 6;
    int c = (e & 63) ^ ((row & 7) << 3);
    gload_lds16(Qg + (size_t)(qt * 128 + row) * 64 + c, &lQ[i * 2048 + wid * 512]);
  }
  __syncthreads();
  short8 aq[2][2];
#pragma unroll
  for (int mi = 0; mi < 2; ++mi)
#pragma unroll
    for (int ks = 0; ks < 2; ++ks)
      aq[mi][ks] = *(const short8*)&lQ[swz(wid * 32 + mi * 16 + ln, ks * 32 + hi * 8)];

  f32x4 ao[2][4];
#pragma unroll
  for (int mi = 0; mi < 2; ++mi)
#pragma unroll
    for (int ni = 0; ni < 4; ++ni) ao[mi][ni] = (f32x4){0.f, 0.f, 0.f, 0.f};

  for (int kt = 0; kt < 32; ++kt) {
    __syncthreads();
#pragma unroll
    for (int i = 0; i < 2; ++i) {
      int e = (i * 256 + t) * 8, row = e >> 6;
      int c = (e & 63) ^ ((row & 7) << 3);
      gload_lds16(Kg + (size_t)(kt * 64 + row) * 64 + c, &lK[i * 2048 + wid * 512]);
      gload_lds16(Vg + (size_t)row * 2048 + kt * 64 + c, &lVt[i * 2048 + wid * 512]);
    }
    __syncthreads();

    // S = Q K^T  (per wave: 32 q-rows x 64 kv)
    f32x4 sa[2][4];
#pragma unroll
    for (int mi = 0; mi < 2; ++mi)
#pragma unroll
      for (int ni = 0; ni < 4; ++ni) sa[mi][ni] = (f32x4){0.f, 0.f, 0.f, 0.f};
#pragma unroll
    for (int ks = 0; ks < 2; ++ks) {
#pragma unroll
      for (int ni = 0; ni < 4; ++ni) {
        short8 bk = *(const short8*)&lK[swz(ni * 16 + ln, ks * 32 + hi * 8)];
        sa[0][ni] = __builtin_amdgcn_mfma_f32_16x16x32_bf16(aq[0][ks], bk, sa[0][ni], 0, 0, 0);
        sa[1][ni] = __builtin_amdgcn_mfma_f32_16x16x32_bf16(aq[1][ks], bk, sa[1][ni], 0, 0, 0);
      }
    }

    // scale + (rare) mask + convert to bf16 P in wave-private LDS region (swizzled writes)
    int flg = flagp[kt];
#pragma unroll
    for (int mi = 0; mi < 2; ++mi)
#pragma unroll
      for (int ni = 0; ni < 4; ++ni) {
        int qrow = wid * 32 + mi * 16 + hi * 4;
        int kcol = ni * 16 + ln;
#pragma unroll
        for (int r = 0; r < 4; ++r) {
          float p = sa[mi][ni][r] * 0.125f;
          if (flg) {
            int mv = maskp[(size_t)(qt * 128 + qrow + r) * 2048 + kt * 64 + kcol];
            if (mv == 0) p = -1e9f;
          }
          lP[swz(qrow + r, kcol)] = f2b(p);
        }
      }

    // O += P @ V   (V staged transposed: lVt[d][kv])
#pragma unroll
    for (int ks = 0; ks < 2; ++ks) {
      short8 ap0 = *(const short8*)&lP[swz(wid * 32 + ln, ks * 32 + hi * 8)];
      short8 ap1 = *(const short8*)&lP[swz(wid * 32 + 16 + ln, ks * 32 + hi * 8)];
#pragma unroll
      for (int ni = 0; ni < 4; ++ni) {
        short8 bv = *(const short8*)&lVt[swz(ni * 16 + ln, ks * 32 + hi * 8)];
        ao[0][ni] = __builtin_amdgcn_mfma_f32_16x16x32_bf16(ap0, bv, ao[0][ni], 0, 0, 0);
        ao[1][ni] = __builtin_amdgcn_mfma_f32_16x16x32_bf16(ap1, bv, ao[1][ni], 0, 0, 0);
      }
    }
  }

  float* op = out + ((size_t)b_ * 2048 + qt * 128) * 1024 + h * 64;
#pragma unroll
  for (int mi = 0; mi < 2; ++mi)
#pragma unroll
    for (int ni = 0; ni < 4; ++ni)
#pragma unroll
      for (int r = 0; r < 4; ++r)
        op[(size_t)(wid * 32 + mi * 16 + hi * 4 + r) * 1024 + ni * 16 + ln] = ao[mi][ni][r];
}

// ---------------- launch ----------------
extern "C" void kernel_launch(void* const* d_in, const int* in_sizes, int n_in,
                              void* d_out, int out_size, void* d_ws, size_t ws_size,
                              hipStream_t stream) {
  const float* x   = (const float*)d_in[0];
  const int*  mask = (const int*)d_in[1];
  const float* wq  = (const float*)d_in[2];
  const float* wk  = (const float*)d_in[3];
  const float* wv  = (const float*)d_in[4];
  float* out = (float*)d_out;

  char* ws = (char*)d_ws;
  const size_t XB_OFF = 0;                 // 16 MiB  x bf16
  const size_t WB_OFF = 16777216;          // 6 MiB   wq|wk|wv bf16
  const size_t QB_OFF = 23068672;          // 16 MiB  Q [b,h,s,d]
  const size_t KB_OFF = 39845888;          // 16 MiB  K [b,h,s,d]
  const size_t VT_OFF = 56623104;          // 16 MiB  V^T [b,h,d,s]
  const size_t FL_OFF = 73400320;          // 8 KiB   tile flags
  if (ws_size < FL_OFF + 8192) return;     // insufficient workspace (unexpected)

  u16* xb  = (u16*)(ws + XB_OFF);
  u16* wb  = (u16*)(ws + WB_OFF);
  u16* qb  = (u16*)(ws + QB_OFF);
  u16* kb  = (u16*)(ws + KB_OFF);
  u16* vtb = (u16*)(ws + VT_OFF);
  int* flags = (int*)(ws + FL_OFF);

  k_convert<<<2048, 256, 0, stream>>>(x, wq, wk, wv, xb, wb);
  k_flags<<<2048, 256, 0, stream>>>(mask, flags);
  k_proj<<<dim3(512, 3), 256, 0, stream>>>(xb, wb, qb, kb, vtb);
  k_attn<<<dim3(16, 64), 256, 0, stream>>>(qb, kb, vtb, mask, flags, out);
}

// Round 6
// 320.993 us; speedup vs baseline: 1.1542x; 1.0184x over previous
//
#include <hip/hip_runtime.h>

// HybridAttention: out[b,s,h*64+d] = sum_k ( mask? (Q·K^T)*0.125 : -1e9 ) * V
// Q=x@wq^T, K=x@wk^T, V=x@wv^T ; B=4,S=2048,D=1024,H=16,dk=64 ; NO softmax.
//
// R5 = R4 with compile fixes: short4 -> s16x4 (HIP predefines short4);
// K=16 bf16 MFMA builtin is __builtin_amdgcn_mfma_f32_16x16x16bf16_1k.
// Attn: swapped QK^T (S^T = K·Q^T) keeps P in registers (S^T D-layout ==
// B-operand layout of mfma_16x16x16) -> PV with no LDS P, no cross-lane ops;
// K/V double-buffered, prefetch-before-compute, ONE barrier per KV tile.

using u16 = unsigned short;
typedef __attribute__((ext_vector_type(8))) short  short8;   // 8 bf16 (4 VGPRs)
typedef __attribute__((ext_vector_type(4))) short  s16x4;    // 4 bf16 (2 VGPRs)
typedef __attribute__((ext_vector_type(4))) float  f32x4;
typedef __attribute__((ext_vector_type(4))) unsigned short u16x4;
typedef __attribute__((ext_vector_type(4))) int    i32x4;

#define DEV static __device__ __forceinline__

DEV u16 f2b(float f) {  // fp32 -> bf16 RNE
  unsigned u = __float_as_uint(f);
  return (u16)((u + 0x7FFFu + ((u >> 16) & 1u)) >> 16);
}

// swizzled u16 index into a [rows][64] u16 LDS tile (row stride 128B)
DEV int swz(int row, int col) { return (row << 6) + (col ^ ((row & 7) << 3)); }

template <typename T>
DEV void gload_lds16(const T* g, T* l) {  // 16B global -> LDS, dest = wave-uniform base + lane*16
  __builtin_amdgcn_global_load_lds((const __attribute__((address_space(1))) unsigned int*)g,
                                   (__attribute__((address_space(3))) unsigned int*)l, 16, 0, 0);
}

// ---------------- convert x, wq, wk, wv to bf16 ----------------
__global__ __launch_bounds__(256) void k_convert(const float* __restrict__ x,
                                                 const float* __restrict__ wq,
                                                 const float* __restrict__ wk,
                                                 const float* __restrict__ wv,
                                                 u16* __restrict__ xb, u16* __restrict__ wb) {
  const int NX4 = 2097152;  // 8388608/4
  const int NW4 = 262144;   // 1048576/4
  const int total = NX4 + 3 * NW4;
  for (int i = blockIdx.x * blockDim.x + threadIdx.x; i < total; i += gridDim.x * blockDim.x) {
    const float4* src; u16* dst; int j;
    if (i < NX4) { src = (const float4*)x; dst = xb; j = i; }
    else {
      int tw = i - NX4; int wsel = tw >> 18; j = tw & (NW4 - 1);
      src = (const float4*)(wsel == 0 ? wq : (wsel == 1 ? wk : wv));
      dst = wb + (size_t)wsel * 1048576;
    }
    float4 v = src[j];
    u16x4 o; o[0] = f2b(v.x); o[1] = f2b(v.y); o[2] = f2b(v.z); o[3] = f2b(v.w);
    *(u16x4*)(dst + (size_t)j * 4) = o;
  }
}

// ---------------- per-tile mask flags: 1 if any zero in (b, qtile128, ktile64) ----------------
__global__ __launch_bounds__(256) void k_flags(const int* __restrict__ mask, int* __restrict__ flags) {
  const int bx = blockIdx.x;                 // 4*16*32 = 2048 tiles
  const int b_ = bx >> 9, rem = bx & 511, qt = rem >> 5, kt = rem & 31;
  const int t = threadIdx.x;
  const size_t base = ((size_t)(b_ * 2048 + qt * 128)) * 2048 + kt * 64;
  int az = 0;
#pragma unroll
  for (int kk = 0; kk < 8; ++kk) {
    int i = t + kk * 256;
    int row = i >> 4, c4 = i & 15;
    i32x4 v = *(const i32x4*)(mask + base + (size_t)row * 2048 + c4 * 4);
    az |= (v.x == 0) | (v.y == 0) | (v.z == 0) | (v.w == 0);
  }
  __shared__ int red[4];
  unsigned long long bal = __ballot(az != 0);
  if ((t & 63) == 0) red[t >> 6] = (bal != 0ull);
  __syncthreads();
  if (t == 0) flags[bx] = red[0] | red[1] | red[2] | red[3];
}

// ---------------- projection GEMM: C[m,n] = sum_k X[m,k] * W[n,k] ----------------
// which=0 -> qb[b,h,s,d], which=1 -> kb[b,h,s,d], which=2 -> vtb[b,h,d,s] (transposed write)
__global__ __launch_bounds__(256, 2) void k_proj(const u16* __restrict__ xb, const u16* __restrict__ wb,
                                                 u16* __restrict__ qb, u16* __restrict__ kb,
                                                 u16* __restrict__ vtb) {
  __shared__ u16 lA[128 * 64];
  __shared__ u16 lB[128 * 64];
  const int t = threadIdx.x, wid = t >> 6, lid = t & 63, ln = lid & 15, hi = lid >> 4;
  const int mt = blockIdx.x >> 3, nt = blockIdx.x & 7, which = blockIdx.y;
  const u16* wsrc = wb + (size_t)which * (1024 * 1024);
  const int wm = wid >> 1, wn = wid & 1;

  f32x4 acc[4][4];
#pragma unroll
  for (int a = 0; a < 4; ++a)
#pragma unroll
    for (int b2 = 0; b2 < 4; ++b2) acc[a][b2] = (f32x4){0.f, 0.f, 0.f, 0.f};

  for (int kt = 0; kt < 16; ++kt) {
    __syncthreads();
#pragma unroll
    for (int i = 0; i < 4; ++i) {
      int e = (i * 256 + t) * 8, row = e >> 6;
      int c = (e & 63) ^ ((row & 7) << 3);  // pre-swizzled global source column
      gload_lds16(xb + (size_t)(mt * 128 + row) * 1024 + kt * 64 + c, &lA[i * 2048 + wid * 512]);
      gload_lds16(wsrc + (size_t)(nt * 128 + row) * 1024 + kt * 64 + c, &lB[i * 2048 + wid * 512]);
    }
    __syncthreads();
#pragma unroll
    for (int ks = 0; ks < 2; ++ks) {
      short8 af[4], bfr[4];
#pragma unroll
      for (int mi = 0; mi < 4; ++mi) af[mi] = *(const short8*)&lA[swz(wm * 64 + mi * 16 + ln, ks * 32 + hi * 8)];
#pragma unroll
      for (int ni = 0; ni < 4; ++ni) bfr[ni] = *(const short8*)&lB[swz(wn * 64 + ni * 16 + ln, ks * 32 + hi * 8)];
#pragma unroll
      for (int mi = 0; mi < 4; ++mi)
#pragma unroll
        for (int ni = 0; ni < 4; ++ni)
          acc[mi][ni] = __builtin_amdgcn_mfma_f32_16x16x32_bf16(af[mi], bfr[ni], acc[mi][ni], 0, 0, 0);
    }
  }

  const int m0 = mt * 128 + wm * 64, n0 = nt * 128 + wn * 64;
  if (which == 2) {
    // V transposed: vtb[((b*16+h)*64+d)*2048 + s] ; lane's 4 regs = 4 consecutive s -> 8B store
#pragma unroll
    for (int mi = 0; mi < 4; ++mi)
#pragma unroll
      for (int ni = 0; ni < 4; ++ni) {
        int mm = m0 + mi * 16 + hi * 4;
        int nn = n0 + ni * 16 + ln;
        int bb = mm >> 11, s0 = mm & 2047, hh = nn >> 6, dd = nn & 63;
        u16x4 pk;
#pragma unroll
        for (int r = 0; r < 4; ++r) pk[r] = f2b(acc[mi][ni][r]);
        *(u16x4*)(vtb + ((size_t)((bb * 16 + hh) * 64 + dd)) * 2048 + s0) = pk;
      }
  } else {
    u16* dst = (which == 1) ? kb : qb;
#pragma unroll
    for (int mi = 0; mi < 4; ++mi)
#pragma unroll
      for (int ni = 0; ni < 4; ++ni) {
        int nn = n0 + ni * 16 + ln;
        int hh = nn >> 6, dd = nn & 63;
#pragma unroll
        for (int r = 0; r < 4; ++r) {
          int m = m0 + mi * 16 + hi * 4 + r;
          int bb = m >> 11, ss = m & 2047;
          dst[((size_t)(bb * 16 + hh) * 2048 + ss) * 64 + dd] = f2b(acc[mi][ni][r]);
        }
      }
  }
}

// ---------------- fused attention (no softmax), in-register P ----------------
// grid: (qtile=16, bh=64). 4 waves, each owns 32 q-rows. BK=64 kv per iter.
// S^T = mfma32(K,Q) -> lane holds P^T[kv=(l>>4)*4+reg][q=l&15] == B-operand of
// mfma_16x16x16 -> O^T[d][q] += mfma16(V^T, P^T). No P staging, no shuffles.
__global__ __launch_bounds__(256, 2) void k_attn(const u16* __restrict__ qb, const u16* __restrict__ kb,
                                                 const u16* __restrict__ vtb, const int* __restrict__ mask,
                                                 const int* __restrict__ flags, float* __restrict__ out) {
  // LDS: [0..8192) buf0 {K[64][64], Vt[64][64]}, [8192..16384) buf1, [16384..24576) Q[128][64]
  __shared__ __align__(16) u16 lds[24576];
  const int t = threadIdx.x, wid = t >> 6, lid = t & 63, ln = lid & 15, hi = lid >> 4;
  const int qt = blockIdx.x, bh = blockIdx.y, b_ = bh >> 4, h = bh & 15;
  const u16* Qg = qb + (size_t)bh * (2048 * 64);
  const u16* Kg = kb + (size_t)bh * (2048 * 64);
  const u16* Vg = vtb + (size_t)bh * (64 * 2048);
  const int* flagp = flags + (b_ * 16 + qt) * 32;
  const int* maskp = mask + (size_t)b_ * (2048 * 2048);
  u16* lQ = lds + 16384;

  // stage Q tile [128][64] (swizzled) + prefetch kt=0 K/V into buf0, one barrier
#pragma unroll
  for (int i = 0; i < 4; ++i) {
    int e = (i * 256 + t) * 8, row = e >> 6;
    int c = (e & 63) ^ ((row & 7) << 3);
    gload_lds16(Qg + (size_t)(qt * 128 + row) * 64 + c, &lQ[i * 2048 + wid * 512]);
  }
#pragma unroll
  for (int i = 0; i < 2; ++i) {
    int e = (i * 256 + t) * 8, row = e >> 6;
    int c = (e & 63) ^ ((row & 7) << 3);
    gload_lds16(Kg + (size_t)row * 64 + c, &lds[i * 2048 + wid * 512]);
    gload_lds16(Vg + (size_t)row * 2048 + c, &lds[4096 + i * 2048 + wid * 512]);
  }
  __syncthreads();

  short8 aq[2][2];
#pragma unroll
  for (int mi = 0; mi < 2; ++mi)
#pragma unroll
    for (int ks = 0; ks < 2; ++ks)
      aq[mi][ks] = *(const short8*)&lQ[swz(wid * 32 + mi * 16 + ln, ks * 32 + hi * 8)];

  f32x4 ot[4][2];  // O^T accumulators: [d-tile][q-tile]
#pragma unroll
  for (int di = 0; di < 4; ++di)
#pragma unroll
    for (int mi = 0; mi < 2; ++mi) ot[di][mi] = (f32x4){0.f, 0.f, 0.f, 0.f};

  int cur = 0;
  for (int kt = 0; kt < 32; ++kt) {
    // prefetch next K/V tile into the other buffer (overlaps with compute below)
    if (kt + 1 < 32) {
#pragma unroll
      for (int i = 0; i < 2; ++i) {
        int e = (i * 256 + t) * 8, row = e >> 6;
        int c = (e & 63) ^ ((row & 7) << 3);
        gload_lds16(Kg + (size_t)((kt + 1) * 64 + row) * 64 + c, &lds[(cur ^ 1) * 8192 + i * 2048 + wid * 512]);
        gload_lds16(Vg + (size_t)row * 2048 + (kt + 1) * 64 + c, &lds[(cur ^ 1) * 8192 + 4096 + i * 2048 + wid * 512]);
      }
    }
    const u16* bK = lds + cur * 8192;
    const u16* bV = lds + cur * 8192 + 4096;

    // S^T[kv][q] = K · Q^T  (per wave: 64 kv x 32 q)
    f32x4 sa[4][2];
#pragma unroll
    for (int ni = 0; ni < 4; ++ni)
#pragma unroll
      for (int mi = 0; mi < 2; ++mi) sa[ni][mi] = (f32x4){0.f, 0.f, 0.f, 0.f};
#pragma unroll
    for (int ks = 0; ks < 2; ++ks) {
      short8 bk[4];
#pragma unroll
      for (int ni = 0; ni < 4; ++ni) bk[ni] = *(const short8*)&bK[swz(ni * 16 + ln, ks * 32 + hi * 8)];
#pragma unroll
      for (int ni = 0; ni < 4; ++ni)
#pragma unroll
        for (int mi = 0; mi < 2; ++mi)
          sa[ni][mi] = __builtin_amdgcn_mfma_f32_16x16x32_bf16(bk[ni], aq[mi][ks], sa[ni][mi], 0, 0, 0);
    }

    // scale + (rare) mask + cvt to bf16 P^T fragments, all in registers
    int flg = flagp[kt];
    s16x4 pt[4][2];
#pragma unroll
    for (int ni = 0; ni < 4; ++ni)
#pragma unroll
      for (int mi = 0; mi < 2; ++mi) {
#pragma unroll
        for (int r = 0; r < 4; ++r) {
          float p = sa[ni][mi][r] * 0.125f;
          if (flg) {
            int qg = qt * 128 + wid * 32 + mi * 16 + ln;
            int kvg = kt * 64 + ni * 16 + hi * 4 + r;
            if (maskp[(size_t)qg * 2048 + kvg] == 0) p = -1e9f;
          }
          pt[ni][mi][r] = (short)f2b(p);
        }
      }

    // O^T += V^T · P^T  via 16x16x16 (kv-step 16)
#pragma unroll
    for (int di = 0; di < 4; ++di) {
      s16x4 vt[4];
#pragma unroll
      for (int ni = 0; ni < 4; ++ni) vt[ni] = *(const s16x4*)&bV[swz(di * 16 + ln, ni * 16 + hi * 4)];
#pragma unroll
      for (int ni = 0; ni < 4; ++ni)
#pragma unroll
        for (int mi = 0; mi < 2; ++mi)
          ot[di][mi] = __builtin_amdgcn_mfma_f32_16x16x16bf16_1k(vt[ni], pt[ni][mi], ot[di][mi], 0, 0, 0);
    }

    __syncthreads();  // drains prefetch (vmcnt 0) + protects buffer swap
    cur ^= 1;
  }

  // O^T lane layout: q = l&15 (col), d = di*16 + (l>>4)*4 + reg (row) -> float4 store
  float* op = out + ((size_t)b_ * 2048 + qt * 128) * 1024 + h * 64;
#pragma unroll
  for (int di = 0; di < 4; ++di)
#pragma unroll
    for (int mi = 0; mi < 2; ++mi) {
      int q = wid * 32 + mi * 16 + ln;
      int d = di * 16 + hi * 4;
      *(f32x4*)(op + (size_t)q * 1024 + d) = ot[di][mi];
    }
}

// ---------------- launch ----------------
extern "C" void kernel_launch(void* const* d_in, const int* in_sizes, int n_in,
                              void* d_out, int out_size, void* d_ws, size_t ws_size,
                              hipStream_t stream) {
  const float* x   = (const float*)d_in[0];
  const int*  mask = (const int*)d_in[1];
  const float* wq  = (const float*)d_in[2];
  const float* wk  = (const float*)d_in[3];
  const float* wv  = (const float*)d_in[4];
  float* out = (float*)d_out;

  char* ws = (char*)d_ws;
  const size_t XB_OFF = 0;                 // 16 MiB  x bf16
  const size_t WB_OFF = 16777216;          // 6 MiB   wq|wk|wv bf16
  const size_t QB_OFF = 23068672;          // 16 MiB  Q [b,h,s,d]
  const size_t KB_OFF = 39845888;          // 16 MiB  K [b,h,s,d]
  const size_t VT_OFF = 56623104;          // 16 MiB  V^T [b,h,d,s]
  const size_t FL_OFF = 73400320;          // 8 KiB   tile flags
  if (ws_size < FL_OFF + 8192) return;     // insufficient workspace (unexpected)

  u16* xb  = (u16*)(ws + XB_OFF);
  u16* wb  = (u16*)(ws + WB_OFF);
  u16* qb  = (u16*)(ws + QB_OFF);
  u16* kb  = (u16*)(ws + KB_OFF);
  u16* vtb = (u16*)(ws + VT_OFF);
  int* flags = (int*)(ws + FL_OFF);

  k_convert<<<2048, 256, 0, stream>>>(x, wq, wk, wv, xb, wb);
  k_flags<<<2048, 256, 0, stream>>>(mask, flags);
  k_proj<<<dim3(512, 3), 256, 0, stream>>>(xb, wb, qb, kb, vtb);
  k_attn<<<dim3(16, 64), 256, 0, stream>>>(qb, kb, vtb, mask, flags, out);
}

// Round 7
// 298.806 us; speedup vs baseline: 1.2399x; 1.0743x over previous
//
#include <hip/hip_runtime.h>
#include <hip/hip_bf16.h>

// HybridAttention: out[b,s,h*64+d] = sum_k ( mask? (Q·K^T)*0.125 : -1e9 ) * V
// Q=x@wq^T, K=x@wk^T, V=x@wv^T ; B=4,S=2048,D=1024,H=16,dk=64 ; NO softmax.
//
// R7 changes (counter-driven, k_attn was MfmaUtil==VALUBusy==38%, occ 24%):
//  - Q pre-scaled by 0.125 in k_proj epilogue -> attn drops 32 muls/iter
//  - f2b integer RNE -> hardware __float2bfloat16 (v_cvt_pk_bf16_f32)
//  - Q fragments loaded global->VGPR directly (lQ LDS dropped: 48->32 KB)
//  - __launch_bounds__(256,4): 4 blocks/CU (was 2)
//  - k_convert + k_flags merged into one k_prep dispatch

using u16 = unsigned short;
typedef __attribute__((ext_vector_type(8))) short  short8;   // 8 bf16 (4 VGPRs)
typedef __attribute__((ext_vector_type(4))) short  s16x4;    // 4 bf16 (2 VGPRs)
typedef __attribute__((ext_vector_type(4))) float  f32x4;
typedef __attribute__((ext_vector_type(4))) unsigned short u16x4;
typedef __attribute__((ext_vector_type(4))) int    i32x4;

#define DEV static __device__ __forceinline__

DEV u16 f2bh(float f) {  // fp32 -> bf16 via HW cvt (compiler pairs into v_cvt_pk_bf16_f32)
  __hip_bfloat16 h = __float2bfloat16(f);
  u16 r; __builtin_memcpy(&r, &h, 2); return r;
}

// swizzled u16 index into a [rows][64] u16 LDS tile (row stride 128B)
DEV int swz(int row, int col) { return (row << 6) + (col ^ ((row & 7) << 3)); }

template <typename T>
DEV void gload_lds16(const T* g, T* l) {  // 16B global -> LDS, dest = wave-uniform base + lane*16
  __builtin_amdgcn_global_load_lds((const __attribute__((address_space(1))) unsigned int*)g,
                                   (__attribute__((address_space(3))) unsigned int*)l, 16, 0, 0);
}

// ---------------- prep: convert x/wq/wk/wv to bf16 (blocks 0..2047) + mask tile flags (2048..4095) ----
__global__ __launch_bounds__(256) void k_prep(const float* __restrict__ x,
                                              const float* __restrict__ wq,
                                              const float* __restrict__ wk,
                                              const float* __restrict__ wv,
                                              const int* __restrict__ mask,
                                              u16* __restrict__ xb, u16* __restrict__ wb,
                                              int* __restrict__ flags) {
  const int t = threadIdx.x;
  if (blockIdx.x < 2048) {
    const int NX4 = 2097152;  // 8388608/4
    const int NW4 = 262144;   // 1048576/4
    const int total = NX4 + 3 * NW4;
    for (int i = blockIdx.x * 256 + t; i < total; i += 2048 * 256) {
      const float4* src; u16* dst; int j;
      if (i < NX4) { src = (const float4*)x; dst = xb; j = i; }
      else {
        int tw = i - NX4; int wsel = tw >> 18; j = tw & (NW4 - 1);
        src = (const float4*)(wsel == 0 ? wq : (wsel == 1 ? wk : wv));
        dst = wb + (size_t)wsel * 1048576;
      }
      float4 v = src[j];
      u16x4 o; o[0] = f2bh(v.x); o[1] = f2bh(v.y); o[2] = f2bh(v.z); o[3] = f2bh(v.w);
      *(u16x4*)(dst + (size_t)j * 4) = o;
    }
  } else {
    const int bx = blockIdx.x - 2048;          // 4*16*32 = 2048 tiles
    const int b_ = bx >> 9, rem = bx & 511, qt = rem >> 5, kt = rem & 31;
    const size_t base = ((size_t)(b_ * 2048 + qt * 128)) * 2048 + kt * 64;
    int az = 0;
#pragma unroll
    for (int kk = 0; kk < 8; ++kk) {
      int i = t + kk * 256;
      int row = i >> 4, c4 = i & 15;
      i32x4 v = *(const i32x4*)(mask + base + (size_t)row * 2048 + c4 * 4);
      az |= (v.x == 0) | (v.y == 0) | (v.z == 0) | (v.w == 0);
    }
    __shared__ int red[4];
    unsigned long long bal = __ballot(az != 0);
    if ((t & 63) == 0) red[t >> 6] = (bal != 0ull);
    __syncthreads();
    if (t == 0) flags[bx] = red[0] | red[1] | red[2] | red[3];
  }
}

// ---------------- projection GEMM: C[m,n] = sum_k X[m,k] * W[n,k] ----------------
// which=0 -> qb[b,h,s,d] (PRE-SCALED by 0.125), which=1 -> kb[b,h,s,d],
// which=2 -> vtb[b,h,d,s] (transposed write)
__global__ __launch_bounds__(256, 2) void k_proj(const u16* __restrict__ xb, const u16* __restrict__ wb,
                                                 u16* __restrict__ qb, u16* __restrict__ kb,
                                                 u16* __restrict__ vtb) {
  __shared__ u16 lA[128 * 64];
  __shared__ u16 lB[128 * 64];
  const int t = threadIdx.x, wid = t >> 6, lid = t & 63, ln = lid & 15, hi = lid >> 4;
  const int mt = blockIdx.x >> 3, nt = blockIdx.x & 7, which = blockIdx.y;
  const u16* wsrc = wb + (size_t)which * (1024 * 1024);
  const int wm = wid >> 1, wn = wid & 1;

  f32x4 acc[4][4];
#pragma unroll
  for (int a = 0; a < 4; ++a)
#pragma unroll
    for (int b2 = 0; b2 < 4; ++b2) acc[a][b2] = (f32x4){0.f, 0.f, 0.f, 0.f};

  for (int kt = 0; kt < 16; ++kt) {
    __syncthreads();
#pragma unroll
    for (int i = 0; i < 4; ++i) {
      int e = (i * 256 + t) * 8, row = e >> 6;
      int c = (e & 63) ^ ((row & 7) << 3);  // pre-swizzled global source column
      gload_lds16(xb + (size_t)(mt * 128 + row) * 1024 + kt * 64 + c, &lA[i * 2048 + wid * 512]);
      gload_lds16(wsrc + (size_t)(nt * 128 + row) * 1024 + kt * 64 + c, &lB[i * 2048 + wid * 512]);
    }
    __syncthreads();
#pragma unroll
    for (int ks = 0; ks < 2; ++ks) {
      short8 af[4], bfr[4];
#pragma unroll
      for (int mi = 0; mi < 4; ++mi) af[mi] = *(const short8*)&lA[swz(wm * 64 + mi * 16 + ln, ks * 32 + hi * 8)];
#pragma unroll
      for (int ni = 0; ni < 4; ++ni) bfr[ni] = *(const short8*)&lB[swz(wn * 64 + ni * 16 + ln, ks * 32 + hi * 8)];
#pragma unroll
      for (int mi = 0; mi < 4; ++mi)
#pragma unroll
        for (int ni = 0; ni < 4; ++ni)
          acc[mi][ni] = __builtin_amdgcn_mfma_f32_16x16x32_bf16(af[mi], bfr[ni], acc[mi][ni], 0, 0, 0);
    }
  }

  const int m0 = mt * 128 + wm * 64, n0 = nt * 128 + wn * 64;
  if (which == 2) {
    // V transposed: vtb[((b*16+h)*64+d)*2048 + s] ; lane's 4 regs = 4 consecutive s -> 8B store
#pragma unroll
    for (int mi = 0; mi < 4; ++mi)
#pragma unroll
      for (int ni = 0; ni < 4; ++ni) {
        int mm = m0 + mi * 16 + hi * 4;
        int nn = n0 + ni * 16 + ln;
        int bb = mm >> 11, s0 = mm & 2047, hh = nn >> 6, dd = nn & 63;
        u16x4 pk;
#pragma unroll
        for (int r = 0; r < 4; ++r) pk[r] = f2bh(acc[mi][ni][r]);
        *(u16x4*)(vtb + ((size_t)((bb * 16 + hh) * 64 + dd)) * 2048 + s0) = pk;
      }
  } else {
    u16* dst = (which == 1) ? kb : qb;
    const float sc = (which == 0) ? 0.125f : 1.0f;  // fold attention scale into Q
#pragma unroll
    for (int mi = 0; mi < 4; ++mi)
#pragma unroll
      for (int ni = 0; ni < 4; ++ni) {
        int nn = n0 + ni * 16 + ln;
        int hh = nn >> 6, dd = nn & 63;
#pragma unroll
        for (int r = 0; r < 4; ++r) {
          int m = m0 + mi * 16 + hi * 4 + r;
          int bb = m >> 11, ss = m & 2047;
          dst[((size_t)(bb * 16 + hh) * 2048 + ss) * 64 + dd] = f2bh(acc[mi][ni][r] * sc);
        }
      }
  }
}

// ---------------- fused attention (no softmax), in-register P ----------------
// grid: (qtile=16, bh=64). 4 waves, each owns 32 q-rows. BK=64 kv per iter.
// S^T = mfma32(K,Q) -> lane holds P^T[kv=(l>>4)*4+reg][q=l&15] == B-operand of
// mfma_16x16x16 -> O^T[d][q] += mfma16(V^T, P^T). No P staging, no shuffles.
// Q pre-scaled; Q fragments live in VGPRs (no lQ); LDS = 2x{K,Vt} = 32 KB.
__global__ __launch_bounds__(256, 4) void k_attn(const u16* __restrict__ qb, const u16* __restrict__ kb,
                                                 const u16* __restrict__ vtb, const int* __restrict__ mask,
                                                 const int* __restrict__ flags, float* __restrict__ out) {
  // LDS: buf = lds + cur*8192 ; K[64][64] at buf, Vt[64][64] at buf+4096
  __shared__ __align__(16) u16 lds[16384];
  const int t = threadIdx.x, wid = t >> 6, lid = t & 63, ln = lid & 15, hi = lid >> 4;
  const int qt = blockIdx.x, bh = blockIdx.y, b_ = bh >> 4, h = bh & 15;
  const u16* Qg = qb + (size_t)bh * (2048 * 64);
  const u16* Kg = kb + (size_t)bh * (2048 * 64);
  const u16* Vg = vtb + (size_t)bh * (64 * 2048);
  const int* flagp = flags + (b_ * 16 + qt) * 32;
  const int* maskp = mask + (size_t)b_ * (2048 * 2048);

  // Q fragments straight to registers (one-time, 4x16B per lane)
  short8 aq[2][2];
#pragma unroll
  for (int mi = 0; mi < 2; ++mi)
#pragma unroll
    for (int ks = 0; ks < 2; ++ks)
      aq[mi][ks] = *(const short8*)(Qg + (size_t)(qt * 128 + wid * 32 + mi * 16 + ln) * 64 + ks * 32 + hi * 8);

  // prefetch kt=0 K/V into buf0
#pragma unroll
  for (int i = 0; i < 2; ++i) {
    int e = (i * 256 + t) * 8, row = e >> 6;
    int c = (e & 63) ^ ((row & 7) << 3);
    gload_lds16(Kg + (size_t)row * 64 + c, &lds[i * 2048 + wid * 512]);
    gload_lds16(Vg + (size_t)row * 2048 + c, &lds[4096 + i * 2048 + wid * 512]);
  }
  __syncthreads();

  f32x4 ot[4][2];  // O^T accumulators: [d-tile][q-tile]
#pragma unroll
  for (int di = 0; di < 4; ++di)
#pragma unroll
    for (int mi = 0; mi < 2; ++mi) ot[di][mi] = (f32x4){0.f, 0.f, 0.f, 0.f};

  int cur = 0;
  for (int kt = 0; kt < 32; ++kt) {
    // prefetch next K/V tile into the other buffer (overlaps with compute below)
    if (kt + 1 < 32) {
#pragma unroll
      for (int i = 0; i < 2; ++i) {
        int e = (i * 256 + t) * 8, row = e >> 6;
        int c = (e & 63) ^ ((row & 7) << 3);
        gload_lds16(Kg + (size_t)((kt + 1) * 64 + row) * 64 + c, &lds[(cur ^ 1) * 8192 + i * 2048 + wid * 512]);
        gload_lds16(Vg + (size_t)row * 2048 + (kt + 1) * 64 + c, &lds[(cur ^ 1) * 8192 + 4096 + i * 2048 + wid * 512]);
      }
    }
    const u16* bK = lds + cur * 8192;
    const u16* bV = lds + cur * 8192 + 4096;

    // S^T[kv][q] = K · Q^T  (per wave: 64 kv x 32 q; Q pre-scaled by 0.125)
    f32x4 sa[4][2];
#pragma unroll
    for (int ni = 0; ni < 4; ++ni)
#pragma unroll
      for (int mi = 0; mi < 2; ++mi) sa[ni][mi] = (f32x4){0.f, 0.f, 0.f, 0.f};
#pragma unroll
    for (int ks = 0; ks < 2; ++ks) {
      short8 bk[4];
#pragma unroll
      for (int ni = 0; ni < 4; ++ni) bk[ni] = *(const short8*)&bK[swz(ni * 16 + ln, ks * 32 + hi * 8)];
#pragma unroll
      for (int ni = 0; ni < 4; ++ni)
#pragma unroll
        for (int mi = 0; mi < 2; ++mi)
          sa[ni][mi] = __builtin_amdgcn_mfma_f32_16x16x32_bf16(bk[ni], aq[mi][ks], sa[ni][mi], 0, 0, 0);
    }

    // (rare) mask + cvt to bf16 P^T fragments, all in registers
    int flg = flagp[kt];
    s16x4 pt[4][2];
#pragma unroll
    for (int ni = 0; ni < 4; ++ni)
#pragma unroll
      for (int mi = 0; mi < 2; ++mi) {
#pragma unroll
        for (int r = 0; r < 4; ++r) {
          float p = sa[ni][mi][r];
          if (flg) {
            int qg = qt * 128 + wid * 32 + mi * 16 + ln;
            int kvg = kt * 64 + ni * 16 + hi * 4 + r;
            if (maskp[(size_t)qg * 2048 + kvg] == 0) p = -1e9f;
          }
          pt[ni][mi][r] = (short)f2bh(p);
        }
      }

    // O^T += V^T · P^T  via 16x16x16 (kv-step 16)
#pragma unroll
    for (int di = 0; di < 4; ++di) {
      s16x4 vt[4];
#pragma unroll
      for (int ni = 0; ni < 4; ++ni) vt[ni] = *(const s16x4*)&bV[swz(di * 16 + ln, ni * 16 + hi * 4)];
#pragma unroll
      for (int ni = 0; ni < 4; ++ni)
#pragma unroll
        for (int mi = 0; mi < 2; ++mi)
          ot[di][mi] = __builtin_amdgcn_mfma_f32_16x16x16bf16_1k(vt[ni], pt[ni][mi], ot[di][mi], 0, 0, 0);
    }

    __syncthreads();  // drains prefetch (vmcnt 0) + protects buffer swap
    cur ^= 1;
  }

  // O^T lane layout: q = l&15 (col), d = di*16 + (l>>4)*4 + reg (row) -> float4 store
  float* op = out + ((size_t)b_ * 2048 + qt * 128) * 1024 + h * 64;
#pragma unroll
  for (int di = 0; di < 4; ++di)
#pragma unroll
    for (int mi = 0; mi < 2; ++mi) {
      int q = wid * 32 + mi * 16 + ln;
      int d = di * 16 + hi * 4;
      *(f32x4*)(op + (size_t)q * 1024 + d) = ot[di][mi];
    }
}

// ---------------- launch ----------------
extern "C" void kernel_launch(void* const* d_in, const int* in_sizes, int n_in,
                              void* d_out, int out_size, void* d_ws, size_t ws_size,
                              hipStream_t stream) {
  const float* x   = (const float*)d_in[0];
  const int*  mask = (const int*)d_in[1];
  const float* wq  = (const float*)d_in[2];
  const float* wk  = (const float*)d_in[3];
  const float* wv  = (const float*)d_in[4];
  float* out = (float*)d_out;

  char* ws = (char*)d_ws;
  const size_t XB_OFF = 0;                 // 16 MiB  x bf16
  const size_t WB_OFF = 16777216;          // 6 MiB   wq|wk|wv bf16
  const size_t QB_OFF = 23068672;          // 16 MiB  Q [b,h,s,d] (pre-scaled)
  const size_t KB_OFF = 39845888;          // 16 MiB  K [b,h,s,d]
  const size_t VT_OFF = 56623104;          // 16 MiB  V^T [b,h,d,s]
  const size_t FL_OFF = 73400320;          // 8 KiB   tile flags
  if (ws_size < FL_OFF + 8192) return;     // insufficient workspace (unexpected)

  u16* xb  = (u16*)(ws + XB_OFF);
  u16* wb  = (u16*)(ws + WB_OFF);
  u16* qb  = (u16*)(ws + QB_OFF);
  u16* kb  = (u16*)(ws + KB_OFF);
  u16* vtb = (u16*)(ws + VT_OFF);
  int* flags = (int*)(ws + FL_OFF);

  k_prep<<<4096, 256, 0, stream>>>(x, wq, wk, wv, mask, xb, wb, flags);
  k_proj<<<dim3(512, 3), 256, 0, stream>>>(xb, wb, qb, kb, vtb);
  k_attn<<<dim3(16, 64), 256, 0, stream>>>(qb, kb, vtb, mask, flags, out);
}

// Round 8
// 270.060 us; speedup vs baseline: 1.3719x; 1.1064x over previous
//
#include <hip/hip_runtime.h>
#include <hip/hip_bf16.h>

// HybridAttention: out[b,s,h*64+d] = sum_k ( mask? (Q·K^T)*0.125 : -1e9 ) * V
// Q=x@wq^T, K=x@wk^T, V=x@wv^T ; B=4,S=2048,D=1024,H=16,dk=64 ; NO softmax.
//
// R8 changes (counter-driven; k_attn FETCH=139MB vs 48MB ideal -> XCD thrash):
//  - k_attn: XCD-chunked block swizzle (id%8==bh%8; 8 bh per XCD = 4MB L2 set)
//  - V stored in FRAGMENT ORDER (kv-in-64 permuted: L = hi*16 + mi*4 + r) so
//    PV reads 8x ds_read_b128 instead of 16x b64
//  - s_setprio(1) around MFMA clusters (T5)
//  - k_proj: XCD-chunked swizzle (id%8==mt%8 -> A-panel L2 reuse)

using u16 = unsigned short;
typedef __attribute__((ext_vector_type(8))) short  short8;   // 8 bf16 (4 VGPRs)
typedef __attribute__((ext_vector_type(4))) short  s16x4;    // 4 bf16 (2 VGPRs)
typedef __attribute__((ext_vector_type(4))) float  f32x4;
typedef __attribute__((ext_vector_type(4))) unsigned short u16x4;
typedef __attribute__((ext_vector_type(4))) int    i32x4;

#define DEV static __device__ __forceinline__

DEV u16 f2bh(float f) {  // fp32 -> bf16 via HW cvt (compiler pairs into v_cvt_pk_bf16_f32)
  __hip_bfloat16 h = __float2bfloat16(f);
  u16 r; __builtin_memcpy(&r, &h, 2); return r;
}

// swizzled u16 index into a [rows][64] u16 LDS tile (row stride 128B)
DEV int swz(int row, int col) { return (row << 6) + (col ^ ((row & 7) << 3)); }

template <typename T>
DEV void gload_lds16(const T* g, T* l) {  // 16B global -> LDS, dest = wave-uniform base + lane*16
  __builtin_amdgcn_global_load_lds((const __attribute__((address_space(1))) unsigned int*)g,
                                   (__attribute__((address_space(3))) unsigned int*)l, 16, 0, 0);
}

// ---------------- prep: convert x/wq/wk/wv to bf16 (blocks 0..2047) + mask tile flags (2048..4095) ----
__global__ __launch_bounds__(256) void k_prep(const float* __restrict__ x,
                                              const float* __restrict__ wq,
                                              const float* __restrict__ wk,
                                              const float* __restrict__ wv,
                                              const int* __restrict__ mask,
                                              u16* __restrict__ xb, u16* __restrict__ wb,
                                              int* __restrict__ flags) {
  const int t = threadIdx.x;
  if (blockIdx.x < 2048) {
    const int NX4 = 2097152;  // 8388608/4
    const int NW4 = 262144;   // 1048576/4
    const int total = NX4 + 3 * NW4;
    for (int i = blockIdx.x * 256 + t; i < total; i += 2048 * 256) {
      const float4* src; u16* dst; int j;
      if (i < NX4) { src = (const float4*)x; dst = xb; j = i; }
      else {
        int tw = i - NX4; int wsel = tw >> 18; j = tw & (NW4 - 1);
        src = (const float4*)(wsel == 0 ? wq : (wsel == 1 ? wk : wv));
        dst = wb + (size_t)wsel * 1048576;
      }
      float4 v = src[j];
      u16x4 o; o[0] = f2bh(v.x); o[1] = f2bh(v.y); o[2] = f2bh(v.z); o[3] = f2bh(v.w);
      *(u16x4*)(dst + (size_t)j * 4) = o;
    }
  } else {
    const int bx = blockIdx.x - 2048;          // 4*16*32 = 2048 tiles
    const int b_ = bx >> 9, rem = bx & 511, qt = rem >> 5, kt = rem & 31;
    const size_t base = ((size_t)(b_ * 2048 + qt * 128)) * 2048 + kt * 64;
    int az = 0;
#pragma unroll
    for (int kk = 0; kk < 8; ++kk) {
      int i = t + kk * 256;
      int row = i >> 4, c4 = i & 15;
      i32x4 v = *(const i32x4*)(mask + base + (size_t)row * 2048 + c4 * 4);
      az |= (v.x == 0) | (v.y == 0) | (v.z == 0) | (v.w == 0);
    }
    __shared__ int red[4];
    unsigned long long bal = __ballot(az != 0);
    if ((t & 63) == 0) red[t >> 6] = (bal != 0ull);
    __syncthreads();
    if (t == 0) flags[bx] = red[0] | red[1] | red[2] | red[3];
  }
}

// ---------------- projection GEMM: C[m,n] = sum_k X[m,k] * W[n,k] ----------------
// which=0 -> qb[b,h,s,d] (PRE-SCALED by 0.125), which=1 -> kb[b,h,s,d],
// which=2 -> vtb[b,h,d,s'] (transposed + kv-in-64 FRAGMENT-ORDER permuted)
__global__ __launch_bounds__(256, 2) void k_proj(const u16* __restrict__ xb, const u16* __restrict__ wb,
                                                 u16* __restrict__ qb, u16* __restrict__ kb,
                                                 u16* __restrict__ vtb) {
  __shared__ u16 lA[128 * 64];
  __shared__ u16 lB[128 * 64];
  const int t = threadIdx.x, wid = t >> 6, lid = t & 63, ln = lid & 15, hi = lid >> 4;
  // XCD-chunked swizzle: id%8 == mt%8 so the 8 nt-blocks of one mt share an XCD L2
  const int id = blockIdx.x;
  const int mt = (id & 7) + 8 * (id >> 6), nt = (id >> 3) & 7, which = blockIdx.y;
  const u16* wsrc = wb + (size_t)which * (1024 * 1024);
  const int wm = wid >> 1, wn = wid & 1;

  f32x4 acc[4][4];
#pragma unroll
  for (int a = 0; a < 4; ++a)
#pragma unroll
    for (int b2 = 0; b2 < 4; ++b2) acc[a][b2] = (f32x4){0.f, 0.f, 0.f, 0.f};

  for (int kt = 0; kt < 16; ++kt) {
    __syncthreads();
#pragma unroll
    for (int i = 0; i < 4; ++i) {
      int e = (i * 256 + t) * 8, row = e >> 6;
      int c = (e & 63) ^ ((row & 7) << 3);  // pre-swizzled global source column
      gload_lds16(xb + (size_t)(mt * 128 + row) * 1024 + kt * 64 + c, &lA[i * 2048 + wid * 512]);
      gload_lds16(wsrc + (size_t)(nt * 128 + row) * 1024 + kt * 64 + c, &lB[i * 2048 + wid * 512]);
    }
    __syncthreads();
#pragma unroll
    for (int ks = 0; ks < 2; ++ks) {
      short8 af[4], bfr[4];
#pragma unroll
      for (int mi = 0; mi < 4; ++mi) af[mi] = *(const short8*)&lA[swz(wm * 64 + mi * 16 + ln, ks * 32 + hi * 8)];
#pragma unroll
      for (int ni = 0; ni < 4; ++ni) bfr[ni] = *(const short8*)&lB[swz(wn * 64 + ni * 16 + ln, ks * 32 + hi * 8)];
#pragma unroll
      for (int mi = 0; mi < 4; ++mi)
#pragma unroll
        for (int ni = 0; ni < 4; ++ni)
          acc[mi][ni] = __builtin_amdgcn_mfma_f32_16x16x32_bf16(af[mi], bfr[ni], acc[mi][ni], 0, 0, 0);
    }
  }

  const int m0 = mt * 128 + wm * 64, n0 = nt * 128 + wn * 64;
  if (which == 2) {
    // V transposed + fragment-order: within each 64-row s-window, store the
    // value for s = mi*16+hi*4+r at offset L = hi*16 + mi*4 + r (8B stores).
#pragma unroll
    for (int mi = 0; mi < 4; ++mi)
#pragma unroll
      for (int ni = 0; ni < 4; ++ni) {
        int nn = n0 + ni * 16 + ln;
        int bb = m0 >> 11, sw = m0 & 2047, hh = nn >> 6, dd = nn & 63;
        u16x4 pk;
#pragma unroll
        for (int r = 0; r < 4; ++r) pk[r] = f2bh(acc[mi][ni][r]);
        *(u16x4*)(vtb + ((size_t)((bb * 16 + hh) * 64 + dd)) * 2048 + sw + hi * 16 + mi * 4) = pk;
      }
  } else {
    u16* dst = (which == 1) ? kb : qb;
    const float sc = (which == 0) ? 0.125f : 1.0f;  // fold attention scale into Q
#pragma unroll
    for (int mi = 0; mi < 4; ++mi)
#pragma unroll
      for (int ni = 0; ni < 4; ++ni) {
        int nn = n0 + ni * 16 + ln;
        int hh = nn >> 6, dd = nn & 63;
#pragma unroll
        for (int r = 0; r < 4; ++r) {
          int m = m0 + mi * 16 + hi * 4 + r;
          int bb = m >> 11, ss = m & 2047;
          dst[((size_t)(bb * 16 + hh) * 2048 + ss) * 64 + dd] = f2bh(acc[mi][ni][r] * sc);
        }
      }
  }
}

// ---------------- fused attention (no softmax), in-register P ----------------
// 1D grid 1024, XCD-chunked: id%8 == bh%8 -> one bh's 16 qt-blocks + 8 bhs/XCD.
// S^T = mfma32(K,Q) -> lane holds P^T[kv=(l>>4)*4+reg][q=l&15] == B-operand of
// mfma_16x16x16 -> O^T[d][q] += mfma16(V^T, P^T). V in fragment order: PV does
// 8x ds_read_b128. Q pre-scaled, Q frags in VGPRs. LDS = 2x{K,Vt} = 32 KB.
__global__ __launch_bounds__(256, 4) void k_attn(const u16* __restrict__ qb, const u16* __restrict__ kb,
                                                 const u16* __restrict__ vtb, const int* __restrict__ mask,
                                                 const int* __restrict__ flags, float* __restrict__ out) {
  __shared__ __align__(16) u16 lds[16384];
  const int t = threadIdx.x, wid = t >> 6, lid = t & 63, ln = lid & 15, hi = lid >> 4;
  const int id = blockIdx.x;
  const int qt = (id >> 3) & 15, bh = (id & 7) + 8 * (id >> 7);
  const int b_ = bh >> 4, h = bh & 15;
  const u16* Qg = qb + (size_t)bh * (2048 * 64);
  const u16* Kg = kb + (size_t)bh * (2048 * 64);
  const u16* Vg = vtb + (size_t)bh * (64 * 2048);
  const int* flagp = flags + (b_ * 16 + qt) * 32;
  const int* maskp = mask + (size_t)b_ * (2048 * 2048);

  // Q fragments straight to registers (one-time, 4x16B per lane)
  short8 aq[2][2];
#pragma unroll
  for (int mi = 0; mi < 2; ++mi)
#pragma unroll
    for (int ks = 0; ks < 2; ++ks)
      aq[mi][ks] = *(const short8*)(Qg + (size_t)(qt * 128 + wid * 32 + mi * 16 + ln) * 64 + ks * 32 + hi * 8);

  // prefetch kt=0 K/V into buf0
#pragma unroll
  for (int i = 0; i < 2; ++i) {
    int e = (i * 256 + t) * 8, row = e >> 6;
    int c = (e & 63) ^ ((row & 7) << 3);
    gload_lds16(Kg + (size_t)row * 64 + c, &lds[i * 2048 + wid * 512]);
    gload_lds16(Vg + (size_t)row * 2048 + c, &lds[4096 + i * 2048 + wid * 512]);
  }
  __syncthreads();

  f32x4 ot[4][2];  // O^T accumulators: [d-tile][q-tile]
#pragma unroll
  for (int di = 0; di < 4; ++di)
#pragma unroll
    for (int mi = 0; mi < 2; ++mi) ot[di][mi] = (f32x4){0.f, 0.f, 0.f, 0.f};

  int cur = 0;
  for (int kt = 0; kt < 32; ++kt) {
    // prefetch next K/V tile into the other buffer (overlaps with compute below)
    if (kt + 1 < 32) {
#pragma unroll
      for (int i = 0; i < 2; ++i) {
        int e = (i * 256 + t) * 8, row = e >> 6;
        int c = (e & 63) ^ ((row & 7) << 3);
        gload_lds16(Kg + (size_t)((kt + 1) * 64 + row) * 64 + c, &lds[(cur ^ 1) * 8192 + i * 2048 + wid * 512]);
        gload_lds16(Vg + (size_t)row * 2048 + (kt + 1) * 64 + c, &lds[(cur ^ 1) * 8192 + 4096 + i * 2048 + wid * 512]);
      }
    }
    const u16* bK = lds + cur * 8192;
    const u16* bV = lds + cur * 8192 + 4096;

    // S^T[kv][q] = K · Q^T  (per wave: 64 kv x 32 q; Q pre-scaled by 0.125)
    f32x4 sa[4][2];
#pragma unroll
    for (int ni = 0; ni < 4; ++ni)
#pragma unroll
      for (int mi = 0; mi < 2; ++mi) sa[ni][mi] = (f32x4){0.f, 0.f, 0.f, 0.f};
    __builtin_amdgcn_s_setprio(1);
#pragma unroll
    for (int ks = 0; ks < 2; ++ks) {
      short8 bk[4];
#pragma unroll
      for (int ni = 0; ni < 4; ++ni) bk[ni] = *(const short8*)&bK[swz(ni * 16 + ln, ks * 32 + hi * 8)];
#pragma unroll
      for (int ni = 0; ni < 4; ++ni)
#pragma unroll
        for (int mi = 0; mi < 2; ++mi)
          sa[ni][mi] = __builtin_amdgcn_mfma_f32_16x16x32_bf16(bk[ni], aq[mi][ks], sa[ni][mi], 0, 0, 0);
    }
    __builtin_amdgcn_s_setprio(0);

    // (rare) mask + cvt to bf16 P^T fragments, all in registers
    int flg = flagp[kt];
    s16x4 pt[4][2];
#pragma unroll
    for (int ni = 0; ni < 4; ++ni)
#pragma unroll
      for (int mi = 0; mi < 2; ++mi) {
#pragma unroll
        for (int r = 0; r < 4; ++r) {
          float p = sa[ni][mi][r];
          if (flg) {
            int qg = qt * 128 + wid * 32 + mi * 16 + ln;
            int kvg = kt * 64 + ni * 16 + hi * 4 + r;
            if (maskp[(size_t)qg * 2048 + kvg] == 0) p = -1e9f;
          }
          pt[ni][mi][r] = (short)f2bh(p);
        }
      }

    // O^T += V^T · P^T  via 16x16x16; V in fragment order -> 2x b128 per di
    __builtin_amdgcn_s_setprio(1);
#pragma unroll
    for (int di = 0; di < 4; ++di) {
      short8 vv0 = *(const short8*)&bV[swz(di * 16 + ln, hi * 16)];
      short8 vv1 = *(const short8*)&bV[swz(di * 16 + ln, hi * 16 + 8)];
      s16x4 vt[4];
      vt[0] = __builtin_shufflevector(vv0, vv0, 0, 1, 2, 3);
      vt[1] = __builtin_shufflevector(vv0, vv0, 4, 5, 6, 7);
      vt[2] = __builtin_shufflevector(vv1, vv1, 0, 1, 2, 3);
      vt[3] = __builtin_shufflevector(vv1, vv1, 4, 5, 6, 7);
#pragma unroll
      for (int ni = 0; ni < 4; ++ni)
#pragma unroll
        for (int mi = 0; mi < 2; ++mi)
          ot[di][mi] = __builtin_amdgcn_mfma_f32_16x16x16bf16_1k(vt[ni], pt[ni][mi], ot[di][mi], 0, 0, 0);
    }
    __builtin_amdgcn_s_setprio(0);

    __syncthreads();  // drains prefetch (vmcnt 0) + protects buffer swap
    cur ^= 1;
  }

  // O^T lane layout: q = l&15 (col), d = di*16 + (l>>4)*4 + reg (row) -> float4 store
  float* op = out + ((size_t)b_ * 2048 + qt * 128) * 1024 + h * 64;
#pragma unroll
  for (int di = 0; di < 4; ++di)
#pragma unroll
    for (int mi = 0; mi < 2; ++mi) {
      int q = wid * 32 + mi * 16 + ln;
      int d = di * 16 + hi * 4;
      *(f32x4*)(op + (size_t)q * 1024 + d) = ot[di][mi];
    }
}

// ---------------- launch ----------------
extern "C" void kernel_launch(void* const* d_in, const int* in_sizes, int n_in,
                              void* d_out, int out_size, void* d_ws, size_t ws_size,
                              hipStream_t stream) {
  const float* x   = (const float*)d_in[0];
  const int*  mask = (const int*)d_in[1];
  const float* wq  = (const float*)d_in[2];
  const float* wk  = (const float*)d_in[3];
  const float* wv  = (const float*)d_in[4];
  float* out = (float*)d_out;

  char* ws = (char*)d_ws;
  const size_t XB_OFF = 0;                 // 16 MiB  x bf16
  const size_t WB_OFF = 16777216;          // 6 MiB   wq|wk|wv bf16
  const size_t QB_OFF = 23068672;          // 16 MiB  Q [b,h,s,d] (pre-scaled)
  const size_t KB_OFF = 39845888;          // 16 MiB  K [b,h,s,d]
  const size_t VT_OFF = 56623104;          // 16 MiB  V^T [b,h,d,s'] fragment-order
  const size_t FL_OFF = 73400320;          // 8 KiB   tile flags
  if (ws_size < FL_OFF + 8192) return;     // insufficient workspace (unexpected)

  u16* xb  = (u16*)(ws + XB_OFF);
  u16* wb  = (u16*)(ws + WB_OFF);
  u16* qb  = (u16*)(ws + QB_OFF);
  u16* kb  = (u16*)(ws + KB_OFF);
  u16* vtb = (u16*)(ws + VT_OFF);
  int* flags = (int*)(ws + FL_OFF);

  k_prep<<<4096, 256, 0, stream>>>(x, wq, wk, wv, mask, xb, wb, flags);
  k_proj<<<dim3(512, 3), 256, 0, stream>>>(xb, wb, qb, kb, vtb);
  k_attn<<<1024, 256, 0, stream>>>(qb, kb, vtb, mask, flags, out);
}

// Round 10
// 258.882 us; speedup vs baseline: 1.4311x; 1.0432x over previous
//
#include <hip/hip_runtime.h>
#include <hip/hip_bf16.h>

// HybridAttention: out[b,s,h*64+d] = sum_k ( mask? (Q·K^T)*0.125 : -1e9 ) * V
// Q=x@wq^T, K=x@wk^T, V=x@wv^T ; B=4,S=2048,D=1024,H=16,dk=64 ; NO softmax.
//
// R9 changes (counter-driven; PV's K=16 MFMA shape was half-rate):
//  - PV now uses mfma_f32_16x16x32 (full rate): P^T fragments repacked
//    in-register from S^T D-layout (kv=hi*4+r per 16-tile) to K=32 B-operand
//    (kv=hi*8+j per 32-block) via v_permlane32_swap + v_permlane16_swap.
//  - V back to plain transposed [b,h,d,s] (fragment-order permutation gone).
//  - k_proj __launch_bounds__(256,3).

using u16 = unsigned short;
typedef __attribute__((ext_vector_type(8))) short  short8;   // 8 bf16 (4 VGPRs)
typedef __attribute__((ext_vector_type(4))) float  f32x4;
typedef __attribute__((ext_vector_type(4))) unsigned short u16x4;
typedef __attribute__((ext_vector_type(4))) unsigned int   u32x4;
typedef __attribute__((ext_vector_type(4))) int    i32x4;

#define DEV static __device__ __forceinline__

DEV u16 f2bh(float f) {  // fp32 -> bf16 via HW cvt
  __hip_bfloat16 h = __float2bfloat16(f);
  u16 r; __builtin_memcpy(&r, &h, 2); return r;
}

DEV unsigned cvtpk(float lo, float hi) {  // {bf16(lo), bf16(hi)} packed in u32
  unsigned r;
  asm("v_cvt_pk_bf16_f32 %0, %1, %2" : "=v"(r) : "v"(lo), "v"(hi));
  return r;
}

DEV short8 u2s8(u32x4 v) { short8 r; __builtin_memcpy(&r, &v, 16); return r; }

// swizzled u16 index into a [rows][64] u16 LDS tile (row stride 128B)
DEV int swz(int row, int col) { return (row << 6) + (col ^ ((row & 7) << 3)); }

template <typename T>
DEV void gload_lds16(const T* g, T* l) {  // 16B global -> LDS, dest = wave-uniform base + lane*16
  __builtin_amdgcn_global_load_lds((const __attribute__((address_space(1))) unsigned int*)g,
                                   (__attribute__((address_space(3))) unsigned int*)l, 16, 0, 0);
}

// ---------------- prep: convert x/wq/wk/wv to bf16 (blocks 0..2047) + mask tile flags (2048..4095) ----
__global__ __launch_bounds__(256) void k_prep(const float* __restrict__ x,
                                              const float* __restrict__ wq,
                                              const float* __restrict__ wk,
                                              const float* __restrict__ wv,
                                              const int* __restrict__ mask,
                                              u16* __restrict__ xb, u16* __restrict__ wb,
                                              int* __restrict__ flags) {
  const int t = threadIdx.x;
  if (blockIdx.x < 2048) {
    const int NX4 = 2097152;  // 8388608/4
    const int NW4 = 262144;   // 1048576/4
    const int total = NX4 + 3 * NW4;
    for (int i = blockIdx.x * 256 + t; i < total; i += 2048 * 256) {
      const float4* src; u16* dst; int j;
      if (i < NX4) { src = (const float4*)x; dst = xb; j = i; }
      else {
        int tw = i - NX4; int wsel = tw >> 18; j = tw & (NW4 - 1);
        src = (const float4*)(wsel == 0 ? wq : (wsel == 1 ? wk : wv));
        dst = wb + (size_t)wsel * 1048576;
      }
      float4 v = src[j];
      u16x4 o; o[0] = f2bh(v.x); o[1] = f2bh(v.y); o[2] = f2bh(v.z); o[3] = f2bh(v.w);
      *(u16x4*)(dst + (size_t)j * 4) = o;
    }
  } else {
    const int bx = blockIdx.x - 2048;          // 4*16*32 = 2048 tiles
    const int b_ = bx >> 9, rem = bx & 511, qt = rem >> 5, kt = rem & 31;
    const size_t base = ((size_t)(b_ * 2048 + qt * 128)) * 2048 + kt * 64;
    int az = 0;
#pragma unroll
    for (int kk = 0; kk < 8; ++kk) {
      int i = t + kk * 256;
      int row = i >> 4, c4 = i & 15;
      i32x4 v = *(const i32x4*)(mask + base + (size_t)row * 2048 + c4 * 4);
      az |= (v.x == 0) | (v.y == 0) | (v.z == 0) | (v.w == 0);
    }
    __shared__ int red[4];
    unsigned long long bal = __ballot(az != 0);
    if ((t & 63) == 0) red[t >> 6] = (bal != 0ull);
    __syncthreads();
    if (t == 0) flags[bx] = red[0] | red[1] | red[2] | red[3];
  }
}

// ---------------- projection GEMM: C[m,n] = sum_k X[m,k] * W[n,k] ----------------
// which=0 -> qb[b,h,s,d] (PRE-SCALED by 0.125), which=1 -> kb[b,h,s,d],
// which=2 -> vtb[b,h,d,s] (transposed write)
__global__ __launch_bounds__(256, 3) void k_proj(const u16* __restrict__ xb, const u16* __restrict__ wb,
                                                 u16* __restrict__ qb, u16* __restrict__ kb,
                                                 u16* __restrict__ vtb) {
  __shared__ u16 lA[128 * 64];
  __shared__ u16 lB[128 * 64];
  const int t = threadIdx.x, wid = t >> 6, lid = t & 63, ln = lid & 15, hi = lid >> 4;
  // XCD-chunked swizzle: id%8 == mt%8 so the 8 nt-blocks of one mt share an XCD L2
  const int id = blockIdx.x;
  const int mt = (id & 7) + 8 * (id >> 6), nt = (id >> 3) & 7, which = blockIdx.y;
  const u16* wsrc = wb + (size_t)which * (1024 * 1024);
  const int wm = wid >> 1, wn = wid & 1;

  f32x4 acc[4][4];
#pragma unroll
  for (int a = 0; a < 4; ++a)
#pragma unroll
    for (int b2 = 0; b2 < 4; ++b2) acc[a][b2] = (f32x4){0.f, 0.f, 0.f, 0.f};

  for (int kt = 0; kt < 16; ++kt) {
    __syncthreads();
#pragma unroll
    for (int i = 0; i < 4; ++i) {
      int e = (i * 256 + t) * 8, row = e >> 6;
      int c = (e & 63) ^ ((row & 7) << 3);  // pre-swizzled global source column
      gload_lds16(xb + (size_t)(mt * 128 + row) * 1024 + kt * 64 + c, &lA[i * 2048 + wid * 512]);
      gload_lds16(wsrc + (size_t)(nt * 128 + row) * 1024 + kt * 64 + c, &lB[i * 2048 + wid * 512]);
    }
    __syncthreads();
#pragma unroll
    for (int ks = 0; ks < 2; ++ks) {
      short8 af[4], bfr[4];
#pragma unroll
      for (int mi = 0; mi < 4; ++mi) af[mi] = *(const short8*)&lA[swz(wm * 64 + mi * 16 + ln, ks * 32 + hi * 8)];
#pragma unroll
      for (int ni = 0; ni < 4; ++ni) bfr[ni] = *(const short8*)&lB[swz(wn * 64 + ni * 16 + ln, ks * 32 + hi * 8)];
#pragma unroll
      for (int mi = 0; mi < 4; ++mi)
#pragma unroll
        for (int ni = 0; ni < 4; ++ni)
          acc[mi][ni] = __builtin_amdgcn_mfma_f32_16x16x32_bf16(af[mi], bfr[ni], acc[mi][ni], 0, 0, 0);
    }
  }

  const int m0 = mt * 128 + wm * 64, n0 = nt * 128 + wn * 64;
  if (which == 2) {
    // V transposed: vtb[((b*16+h)*64+d)*2048 + s] ; lane's 4 regs = 4 consecutive s -> 8B store
#pragma unroll
    for (int mi = 0; mi < 4; ++mi)
#pragma unroll
      for (int ni = 0; ni < 4; ++ni) {
        int mm = m0 + mi * 16 + hi * 4;
        int nn = n0 + ni * 16 + ln;
        int bb = mm >> 11, s0 = mm & 2047, hh = nn >> 6, dd = nn & 63;
        u16x4 pk;
#pragma unroll
        for (int r = 0; r < 4; ++r) pk[r] = f2bh(acc[mi][ni][r]);
        *(u16x4*)(vtb + ((size_t)((bb * 16 + hh) * 64 + dd)) * 2048 + s0) = pk;
      }
  } else {
    u16* dst = (which == 1) ? kb : qb;
    const float sc = (which == 0) ? 0.125f : 1.0f;  // fold attention scale into Q
#pragma unroll
    for (int mi = 0; mi < 4; ++mi)
#pragma unroll
      for (int ni = 0; ni < 4; ++ni) {
        int nn = n0 + ni * 16 + ln;
        int hh = nn >> 6, dd = nn & 63;
#pragma unroll
        for (int r = 0; r < 4; ++r) {
          int m = m0 + mi * 16 + hi * 4 + r;
          int bb = m >> 11, ss = m & 2047;
          dst[((size_t)(bb * 16 + hh) * 2048 + ss) * 64 + dd] = f2bh(acc[mi][ni][r] * sc);
        }
      }
  }
}

// ---------------- fused attention (no softmax), in-register P, full-rate PV ----
// 1D grid 1024, XCD-chunked: id%8 == bh%8 -> one bh's 16 qt-blocks + 8 bhs/XCD.
// S^T = mfma32(K,Q): lane holds P^T[kv=ni*16+hi*4+r][q=l&15]. Repack pairs of
// 16-tiles into K=32 B-operand (kv=hi*8+j) via permlane32+16 swaps, then
// O^T[d][q] += mfma_16x16x32(V^T-frag, P^T-frag). LDS = 2x{K,Vt} = 32 KB.
__global__ __launch_bounds__(256, 4) void k_attn(const u16* __restrict__ qb, const u16* __restrict__ kb,
                                                 const u16* __restrict__ vtb, const int* __restrict__ mask,
                                                 const int* __restrict__ flags, float* __restrict__ out) {
  __shared__ __align__(16) u16 lds[16384];
  const int t = threadIdx.x, wid = t >> 6, lid = t & 63, ln = lid & 15, hi = lid >> 4;
  const int id = blockIdx.x;
  const int qt = (id >> 3) & 15, bh = (id & 7) + 8 * (id >> 7);
  const int b_ = bh >> 4, h = bh & 15;
  const u16* Qg = qb + (size_t)bh * (2048 * 64);
  const u16* Kg = kb + (size_t)bh * (2048 * 64);
  const u16* Vg = vtb + (size_t)bh * (64 * 2048);
  const int* flagp = flags + (b_ * 16 + qt) * 32;
  const int* maskp = mask + (size_t)b_ * (2048 * 2048);

  // Q fragments straight to registers (one-time, 4x16B per lane)
  short8 aq[2][2];
#pragma unroll
  for (int mi = 0; mi < 2; ++mi)
#pragma unroll
    for (int ks = 0; ks < 2; ++ks)
      aq[mi][ks] = *(const short8*)(Qg + (size_t)(qt * 128 + wid * 32 + mi * 16 + ln) * 64 + ks * 32 + hi * 8);

  // prefetch kt=0 K/V into buf0
#pragma unroll
  for (int i = 0; i < 2; ++i) {
    int e = (i * 256 + t) * 8, row = e >> 6;
    int c = (e & 63) ^ ((row & 7) << 3);
    gload_lds16(Kg + (size_t)row * 64 + c, &lds[i * 2048 + wid * 512]);
    gload_lds16(Vg + (size_t)row * 2048 + c, &lds[4096 + i * 2048 + wid * 512]);
  }
  __syncthreads();

  f32x4 ot[4][2];  // O^T accumulators: [d-tile][q-tile]
#pragma unroll
  for (int di = 0; di < 4; ++di)
#pragma unroll
    for (int mi = 0; mi < 2; ++mi) ot[di][mi] = (f32x4){0.f, 0.f, 0.f, 0.f};

  int cur = 0;
  for (int kt = 0; kt < 32; ++kt) {
    // prefetch next K/V tile into the other buffer (overlaps with compute below)
    if (kt + 1 < 32) {
#pragma unroll
      for (int i = 0; i < 2; ++i) {
        int e = (i * 256 + t) * 8, row = e >> 6;
        int c = (e & 63) ^ ((row & 7) << 3);
        gload_lds16(Kg + (size_t)((kt + 1) * 64 + row) * 64 + c, &lds[(cur ^ 1) * 8192 + i * 2048 + wid * 512]);
        gload_lds16(Vg + (size_t)row * 2048 + (kt + 1) * 64 + c, &lds[(cur ^ 1) * 8192 + 4096 + i * 2048 + wid * 512]);
      }
    }
    const u16* bK = lds + cur * 8192;
    const u16* bV = lds + cur * 8192 + 4096;

    // S^T[kv][q] = K · Q^T  (per wave: 64 kv x 32 q; Q pre-scaled by 0.125)
    f32x4 sa[4][2];
#pragma unroll
    for (int ni = 0; ni < 4; ++ni)
#pragma unroll
      for (int mi = 0; mi < 2; ++mi) sa[ni][mi] = (f32x4){0.f, 0.f, 0.f, 0.f};
    __builtin_amdgcn_s_setprio(1);
#pragma unroll
    for (int ks = 0; ks < 2; ++ks) {
      short8 bk[4];
#pragma unroll
      for (int ni = 0; ni < 4; ++ni) bk[ni] = *(const short8*)&bK[swz(ni * 16 + ln, ks * 32 + hi * 8)];
#pragma unroll
      for (int ni = 0; ni < 4; ++ni)
#pragma unroll
        for (int mi = 0; mi < 2; ++mi)
          sa[ni][mi] = __builtin_amdgcn_mfma_f32_16x16x32_bf16(bk[ni], aq[mi][ks], sa[ni][mi], 0, 0, 0);
    }
    __builtin_amdgcn_s_setprio(0);

    // (rare) mask on S^T in registers
    if (flagp[kt]) {
#pragma unroll
      for (int ni = 0; ni < 4; ++ni)
#pragma unroll
        for (int mi = 0; mi < 2; ++mi)
#pragma unroll
          for (int r = 0; r < 4; ++r) {
            int qg = qt * 128 + wid * 32 + mi * 16 + ln;
            int kvg = kt * 64 + ni * 16 + hi * 4 + r;
            if (maskp[(size_t)qg * 2048 + kvg] == 0) sa[ni][mi][r] = -1e9f;
          }
    }

    // repack P^T pairs (16-tiles 2nb,2nb+1) into K=32 B-operand fragments:
    // dest lane group G=hi gets kv {8G..8G+7} of the 32-block. After
    // swap32: a=[a_lo,b_lo], b=[a_hi,b_hi]; after swap16: a=w_even, b=w_odd.
    u32x4 pb[2][2];
#pragma unroll
    for (int nb = 0; nb < 2; ++nb)
#pragma unroll
      for (int mi = 0; mi < 2; ++mi) {
        unsigned a0 = cvtpk(sa[2 * nb][mi][0], sa[2 * nb][mi][1]);
        unsigned a1 = cvtpk(sa[2 * nb][mi][2], sa[2 * nb][mi][3]);
        unsigned b0 = cvtpk(sa[2 * nb + 1][mi][0], sa[2 * nb + 1][mi][1]);
        unsigned b1 = cvtpk(sa[2 * nb + 1][mi][2], sa[2 * nb + 1][mi][3]);
        asm("v_permlane32_swap_b32 %0, %1" : "+v"(a0), "+v"(b0));
        asm("v_permlane32_swap_b32 %0, %1" : "+v"(a1), "+v"(b1));
        asm("v_permlane16_swap_b32 %0, %1" : "+v"(a0), "+v"(b0));
        asm("v_permlane16_swap_b32 %0, %1" : "+v"(a1), "+v"(b1));
        pb[nb][mi] = (u32x4){a0, a1, b0, b1};  // = B-frag words j{0,1}{2,3}{4,5}{6,7}
      }

    // O^T += V^T · P^T via 16x16x32 (full rate): per di, 2 kv32-blocks
    __builtin_amdgcn_s_setprio(1);
#pragma unroll
    for (int di = 0; di < 4; ++di) {
      short8 v0 = *(const short8*)&bV[swz(di * 16 + ln, hi * 8)];
      short8 v1 = *(const short8*)&bV[swz(di * 16 + ln, 32 + hi * 8)];
#pragma unroll
      for (int mi = 0; mi < 2; ++mi) {
        ot[di][mi] = __builtin_amdgcn_mfma_f32_16x16x32_bf16(v0, u2s8(pb[0][mi]), ot[di][mi], 0, 0, 0);
        ot[di][mi] = __builtin_amdgcn_mfma_f32_16x16x32_bf16(v1, u2s8(pb[1][mi]), ot[di][mi], 0, 0, 0);
      }
    }
    __builtin_amdgcn_s_setprio(0);

    __syncthreads();  // drains prefetch (vmcnt 0) + protects buffer swap
    cur ^= 1;
  }

  // O^T lane layout: q = l&15 (col), d = di*16 + (l>>4)*4 + reg (row) -> float4 store
  float* op = out + ((size_t)b_ * 2048 + qt * 128) * 1024 + h * 64;
#pragma unroll
  for (int di = 0; di < 4; ++di)
#pragma unroll
    for (int mi = 0; mi < 2; ++mi) {
      int q = wid * 32 + mi * 16 + ln;
      int d = di * 16 + hi * 4;
      *(f32x4*)(op + (size_t)q * 1024 + d) = ot[di][mi];
    }
}

// ---------------- launch ----------------
extern "C" void kernel_launch(void* const* d_in, const int* in_sizes, int n_in,
                              void* d_out, int out_size, void* d_ws, size_t ws_size,
                              hipStream_t stream) {
  const float* x   = (const float*)d_in[0];
  const int*  mask = (const int*)d_in[1];
  const float* wq  = (const float*)d_in[2];
  const float* wk  = (const float*)d_in[3];
  const float* wv  = (const float*)d_in[4];
  float* out = (float*)d_out;

  char* ws = (char*)d_ws;
  const size_t XB_OFF = 0;                 // 16 MiB  x bf16
  const size_t WB_OFF = 16777216;          // 6 MiB   wq|wk|wv bf16
  const size_t QB_OFF = 23068672;          // 16 MiB  Q [b,h,s,d] (pre-scaled)
  const size_t KB_OFF = 39845888;          // 16 MiB  K [b,h,s,d]
  const size_t VT_OFF = 56623104;          // 16 MiB  V^T [b,h,d,s]
  const size_t FL_OFF = 73400320;          // 8 KiB   tile flags
  if (ws_size < FL_OFF + 8192) return;     // insufficient workspace (unexpected)

  u16* xb  = (u16*)(ws + XB_OFF);
  u16* wb  = (u16*)(ws + WB_OFF);
  u16* qb  = (u16*)(ws + QB_OFF);
  u16* kb  = (u16*)(ws + KB_OFF);
  u16* vtb = (u16*)(ws + VT_OFF);
  int* flags = (int*)(ws + FL_OFF);

  k_prep<<<4096, 256, 0, stream>>>(x, wq, wk, wv, mask, xb, wb, flags);
  k_proj<<<dim3(512, 3), 256, 0, stream>>>(xb, wb, qb, kb, vtb);
  k_attn<<<1024, 256, 0, stream>>>(qb, kb, vtb, mask, flags, out);
}